// Round 9
// baseline (323.359 us; speedup 1.0000x reference)
//
#include <hip/hip_runtime.h>

#define DIM 128      // feature dim, fixed per reference
#define GTM 32       // fused tile rows (nodes per block)
#define NCH 8        // colscan chunks
#define CH  30       // copies per chunk
#define HB  (NCH*CH) // 240 histogram copies ~= CU count (1 block/CU, 100KB LDS)
#define HWORDS 25088 // max (N+1)/2 supported by LDS histogram (100,352 B)

// ---------------- LDS-privatized dual histogram + rank capture ----------------
__global__ __launch_bounds__(256) void k_hist(const int* __restrict__ src,
                                              const int* __restrict__ dst,
                                              unsigned short* __restrict__ local,
                                              unsigned* __restrict__ hist_in,
                                              unsigned* __restrict__ hist_out,
                                              int E, int W2, int slice) {
    __shared__ unsigned h[HWORDS];
    const int t = threadIdx.x;
    const int b = blockIdx.x;
    const int e0 = b * slice;
    const int e1 = min(e0 + slice, E);

    for (int w = t; w < W2; w += 256) h[w] = 0u;
    __syncthreads();
    for (int e = e0 + t; e < e1; e += 256) {
        int d = dst[e];
        unsigned sh = (unsigned)(d & 1) * 16u;
        unsigned old = atomicAdd(&h[d >> 1], 1u << sh);
        local[e] = (unsigned short)((old >> sh) & 0xffffu);
    }
    __syncthreads();
    unsigned* oin = hist_in + (size_t)b * W2;
    for (int w = t; w < W2; w += 256) { oin[w] = h[w]; h[w] = 0u; }
    __syncthreads();
    for (int e = e0 + t; e < e1; e += 256) {
        int s = src[e];
        atomicAdd(&h[s >> 1], 1u << ((unsigned)(s & 1) * 16u));
    }
    __syncthreads();
    unsigned* oout = hist_out + (size_t)b * W2;
    for (int w = t; w < W2; w += 256) oout[w] = h[w];
}

// ---------------- colscan pass 1: in-chunk exclusive prefix + chunk totals ----------------
__global__ __launch_bounds__(256) void k_colscan1(unsigned* __restrict__ hist_in,
                                                  const unsigned* __restrict__ hist_out,
                                                  unsigned* __restrict__ aux_in,
                                                  unsigned* __restrict__ aux_out, int W2) {
    int w = blockIdx.x * 256 + threadIdx.x;
    if (w >= W2) return;
    int ch = blockIdx.y;
    size_t base = (size_t)ch * CH * W2 + w;
    unsigned run = 0;
    #pragma unroll 5
    for (int b = 0; b < CH; ++b) {
        unsigned* p = hist_in + base + (size_t)b * W2;
        unsigned x = *p;
        *p = run;          // in-chunk exclusive packed prefix
        run += x;          // halves independent (each < 65536)
    }
    aux_in[(size_t)ch * W2 + w] = run;
    unsigned run2 = 0;
    #pragma unroll 5
    for (int b = 0; b < CH; ++b) run2 += hist_out[base + (size_t)b * W2];
    aux_out[(size_t)ch * W2 + w] = run2;
}

// ---------------- colscan pass 2: scan chunk totals -> bases; totals -> cnt/deg_out ----------------
__global__ __launch_bounds__(256) void k_colscan2(unsigned* __restrict__ aux_in,
                                                  const unsigned* __restrict__ aux_out,
                                                  int* __restrict__ cnt,
                                                  int* __restrict__ deg_out,
                                                  int W2, int N) {
    int w = blockIdx.x * 256 + threadIdx.x;
    if (w >= W2) return;
    unsigned run = 0, run2 = 0;
    #pragma unroll
    for (int ch = 0; ch < NCH; ++ch) {
        unsigned x = aux_in[(size_t)ch * W2 + w];
        aux_in[(size_t)ch * W2 + w] = run;   // chunk base
        run += x;
        run2 += aux_out[(size_t)ch * W2 + w];
    }
    int n0 = w * 2, n1 = n0 + 1;
    cnt[n0] = (int)(run & 0xffffu);
    deg_out[n0] = (int)(run2 & 0xffffu);
    if (n1 < N) {
        cnt[n1] = (int)(run >> 16);
        deg_out[n1] = (int)(run2 >> 16);
    }
}

// ---------------- fallback edge pass (global atomics) for oversized N ----------------
__global__ __launch_bounds__(256) void k_edge_pass_fb(const int* __restrict__ src,
                                                      const int* __restrict__ dst,
                                                      int* __restrict__ deg_out,
                                                      int* __restrict__ cnt,
                                                      int* __restrict__ local_fb, int E) {
    int e = blockIdx.x * 256 + threadIdx.x;
    if (e < E) {
        atomicAdd(&deg_out[src[e]], 1);
        local_fb[e] = atomicAdd(&cnt[dst[e]], 1);
    }
}

// ---------------- scan step 1: per-block sums of cnt ----------------
__global__ __launch_bounds__(256) void k_block_reduce(const int* __restrict__ deg,
                                                      int* __restrict__ bsum, int N) {
    __shared__ int wsum[4];
    int i = blockIdx.x * 256 + threadIdx.x;
    int x = (i < N) ? deg[i] : 0;
    #pragma unroll
    for (int off = 32; off > 0; off >>= 1) x += __shfl_down(x, off, 64);
    int lane = threadIdx.x & 63, wave = threadIdx.x >> 6;
    if (lane == 0) wsum[wave] = x;
    __syncthreads();
    if (threadIdx.x == 0) bsum[blockIdx.x] = wsum[0] + wsum[1] + wsum[2] + wsum[3];
}

// ---------------- scan step 2: exclusive scan of block sums (1 block) ----------------
__global__ __launch_bounds__(256) void k_scan_small(const int* __restrict__ bsum,
                                                    int* __restrict__ bpre, int B) {
    __shared__ int wsum[4];
    __shared__ int carry_s;
    if (threadIdx.x == 0) carry_s = 0;
    __syncthreads();
    int lane = threadIdx.x & 63, wave = threadIdx.x >> 6;
    for (int base = 0; base < B; base += 256) {
        int i = base + threadIdx.x;
        int x = (i < B) ? bsum[i] : 0;
        int orig = x;
        #pragma unroll
        for (int off = 1; off < 64; off <<= 1) {
            int y = __shfl_up(x, off, 64);
            if (lane >= off) x += y;
        }
        if (lane == 63) wsum[wave] = x;
        __syncthreads();
        if (threadIdx.x == 0) {
            int s = 0;
            for (int w = 0; w < 4; ++w) { int t = wsum[w]; wsum[w] = s; s += t; }
        }
        __syncthreads();
        x += wsum[wave] + carry_s;
        if (i < B) bpre[i] = x - orig;
        __syncthreads();
        if (threadIdx.x == 255) carry_s = x;
        __syncthreads();
    }
}

// ---------------- scan step 3: row_off + both norms (fused) ----------------
__global__ __launch_bounds__(256) void k_scan_final(const int* __restrict__ cnt,
                                                    const int* __restrict__ deg_out,
                                                    const int* __restrict__ bpre,
                                                    int* __restrict__ row_off,
                                                    float* __restrict__ norm_src,
                                                    float* __restrict__ norm_dst, int N) {
    __shared__ int wsum[4];
    int i = blockIdx.x * 256 + threadIdx.x;
    int x = (i < N) ? cnt[i] : 0;
    int orig = x;
    int lane = threadIdx.x & 63, wave = threadIdx.x >> 6;
    #pragma unroll
    for (int off = 1; off < 64; off <<= 1) {
        int y = __shfl_up(x, off, 64);
        if (lane >= off) x += y;
    }
    if (lane == 63) wsum[wave] = x;
    __syncthreads();
    if (threadIdx.x == 0) {
        int s = 0;
        for (int w = 0; w < 4; ++w) { int t = wsum[w]; wsum[w] = s; s += t; }
    }
    __syncthreads();
    x += wsum[wave] + bpre[blockIdx.x];
    if (i < N) {
        row_off[i] = x - orig;
        int di = orig < 1 ? 1 : orig;
        norm_dst[i] = rsqrtf((float)di);
        int dov = deg_out[i]; if (dov < 1) dov = 1;
        norm_src[i] = rsqrtf((float)dov);
    }
    if (i == N - 1) row_off[N] = x;
}

// ---------------- CSR fill: pure scatter, no atomics ----------------
__global__ __launch_bounds__(256) void k_fill(const int* __restrict__ src,
                                              const int* __restrict__ dst,
                                              const int* __restrict__ row_off,
                                              const unsigned short* __restrict__ local,
                                              const int* __restrict__ local_fb,
                                              const unsigned* __restrict__ hist_in,
                                              const unsigned* __restrict__ aux_in,
                                              int* __restrict__ csr_src,
                                              int E, int W2, int slice) {
    int e = blockIdx.x * 256 + threadIdx.x;
    if (e < E) {
        int d = dst[e];
        int pos = row_off[d];
        if (hist_in) {
            int b = e / slice;
            int ch = b / CH;
            unsigned sh = (unsigned)(d & 1) * 16u;
            unsigned bo = (hist_in[(size_t)b * W2 + (d >> 1)] >> sh) & 0xffffu;
            unsigned cb = (aux_in[(size_t)ch * W2 + (d >> 1)] >> sh) & 0xffffu;
            pos += (int)bo + (int)cb + (int)local[e];
        } else {
            pos += local_fb[e];
        }
        csr_src[pos] = src[e];
    }
}

// ---------------- fused SpMM + GEMM: out = [ps ⊙] relu((nd ⊙ Agg(h)) @ W + b) ----------------
// Block: 256 threads, 32 nodes. Phase 1: 8 half-wave groups gather 4 nodes each
// into LDS rows (32x128, 16 KB) while W (64 KB) stages -> exactly 80 KB LDS,
// 2 blocks/CU. Phase 2: 32x128 GEMM, 4x4 acc/thread, rows/W from LDS.
__global__ __launch_bounds__(256, 2) void k_spmm_gemm(
        const float* __restrict__ h,
        const int* __restrict__ csr_src,
        const int* __restrict__ row_off,
        const float* __restrict__ norm_src,   // null => h pre-scaled
        const float* __restrict__ norm_dst,
        const float* __restrict__ W,
        const float* __restrict__ bias,
        const float* __restrict__ postscale,  // null => none
        float* __restrict__ out, int N) {
    __shared__ float Ws[DIM * DIM];   // [k][c] 64 KB
    __shared__ float R[GTM * DIM];    // aggregated rows, 16 KB

    const int t = threadIdx.x;
    const int row0 = blockIdx.x * GTM;

    // stage all of W: 16 float4/thread (issued first; drained at syncthreads)
    #pragma unroll
    for (int i = 0; i < 16; ++i) {
        int idx = (t + i * 256) * 4;
        *(float4*)(Ws + idx) = *(const float4*)(W + idx);
    }

    // ---- phase 1: gather 32 rows into R ----
    const int grp = t >> 5;      // 0..7
    const int lane = t & 31;
    for (int nl = grp; nl < GTM; nl += 8) {
        int node = row0 + nl;
        float4 acc0 = make_float4(0.f, 0.f, 0.f, 0.f);
        float4 acc1 = make_float4(0.f, 0.f, 0.f, 0.f);
        float nd = 0.f;
        if (node < N) {
            int beg = row_off[node], end = row_off[node + 1];
            int i = beg;
            if (norm_src) {
                for (; i + 4 <= end; i += 4) {
                    int s0 = csr_src[i], s1 = csr_src[i + 1], s2 = csr_src[i + 2], s3 = csr_src[i + 3];
                    float n0 = norm_src[s0], n1 = norm_src[s1], n2 = norm_src[s2], n3 = norm_src[s3];
                    float4 v0 = *((const float4*)(h + (size_t)s0 * DIM) + lane);
                    float4 v1 = *((const float4*)(h + (size_t)s1 * DIM) + lane);
                    float4 v2 = *((const float4*)(h + (size_t)s2 * DIM) + lane);
                    float4 v3 = *((const float4*)(h + (size_t)s3 * DIM) + lane);
                    acc0.x += v0.x * n0; acc0.y += v0.y * n0; acc0.z += v0.z * n0; acc0.w += v0.w * n0;
                    acc1.x += v1.x * n1; acc1.y += v1.y * n1; acc1.z += v1.z * n1; acc1.w += v1.w * n1;
                    acc0.x += v2.x * n2; acc0.y += v2.y * n2; acc0.z += v2.z * n2; acc0.w += v2.w * n2;
                    acc1.x += v3.x * n3; acc1.y += v3.y * n3; acc1.z += v3.z * n3; acc1.w += v3.w * n3;
                }
                for (; i < end; ++i) {
                    int s0 = csr_src[i];
                    float n0 = norm_src[s0];
                    float4 v0 = *((const float4*)(h + (size_t)s0 * DIM) + lane);
                    acc0.x += v0.x * n0; acc0.y += v0.y * n0; acc0.z += v0.z * n0; acc0.w += v0.w * n0;
                }
            } else {
                for (; i + 4 <= end; i += 4) {
                    int s0 = csr_src[i], s1 = csr_src[i + 1], s2 = csr_src[i + 2], s3 = csr_src[i + 3];
                    float4 v0 = *((const float4*)(h + (size_t)s0 * DIM) + lane);
                    float4 v1 = *((const float4*)(h + (size_t)s1 * DIM) + lane);
                    float4 v2 = *((const float4*)(h + (size_t)s2 * DIM) + lane);
                    float4 v3 = *((const float4*)(h + (size_t)s3 * DIM) + lane);
                    acc0.x += v0.x; acc0.y += v0.y; acc0.z += v0.z; acc0.w += v0.w;
                    acc1.x += v1.x; acc1.y += v1.y; acc1.z += v1.z; acc1.w += v1.w;
                    acc0.x += v2.x; acc0.y += v2.y; acc0.z += v2.z; acc0.w += v2.w;
                    acc1.x += v3.x; acc1.y += v3.y; acc1.z += v3.z; acc1.w += v3.w;
                }
                for (; i < end; ++i) {
                    int s0 = csr_src[i];
                    float4 v0 = *((const float4*)(h + (size_t)s0 * DIM) + lane);
                    acc0.x += v0.x; acc0.y += v0.y; acc0.z += v0.z; acc0.w += v0.w;
                }
            }
            nd = norm_dst[node];
        }
        float4 r;
        r.x = (acc0.x + acc1.x) * nd;
        r.y = (acc0.y + acc1.y) * nd;
        r.z = (acc0.z + acc1.z) * nd;
        r.w = (acc0.w + acc1.w) * nd;
        *(float4*)(R + nl * DIM + lane * 4) = r;
    }
    __syncthreads();

    // ---- phase 2: 32x128 GEMM from LDS ----
    const int tx = t & 31;    // col group -> cols tx*4..+3
    const int ty = t >> 5;    // row group -> rows ty*4..+3
    const int c0t = tx * 4;

    float acc[4][4];
    #pragma unroll
    for (int i = 0; i < 4; ++i)
        #pragma unroll
        for (int j = 0; j < 4; ++j) acc[i][j] = 0.f;

    #pragma unroll 4
    for (int k = 0; k < DIM; k += 4) {
        float a[4][4];
        float w[4][4];
        #pragma unroll
        for (int i = 0; i < 4; ++i)
            *(float4*)a[i] = *(const float4*)(R + (ty * 4 + i) * DIM + k);
        #pragma unroll
        for (int kk = 0; kk < 4; ++kk)
            *(float4*)w[kk] = *(const float4*)(Ws + (k + kk) * DIM + c0t);
        #pragma unroll
        for (int kk = 0; kk < 4; ++kk)
            #pragma unroll
            for (int i = 0; i < 4; ++i)
                #pragma unroll
                for (int j = 0; j < 4; ++j)
                    acc[i][j] += a[i][kk] * w[kk][j];
    }

    float bb[4];
    #pragma unroll
    for (int j = 0; j < 4; ++j) bb[j] = bias[c0t + j];
    #pragma unroll
    for (int i = 0; i < 4; ++i) {
        int gr = row0 + ty * 4 + i;
        if (gr < N) {
            float s = postscale ? postscale[gr] : 1.f;
            float4 o;
            o.x = fmaxf(acc[i][0] + bb[0], 0.f) * s;
            o.y = fmaxf(acc[i][1] + bb[1], 0.f) * s;
            o.z = fmaxf(acc[i][2] + bb[2], 0.f) * s;
            o.w = fmaxf(acc[i][3] + bb[3], 0.f) * s;
            *(float4*)(out + (size_t)gr * DIM + c0t) = o;
        }
    }
}

static inline size_t align_up(size_t x, size_t a) { return (x + a - 1) & ~(a - 1); }

extern "C" void kernel_launch(void* const* d_in, const int* in_sizes, int n_in,
                              void* d_out, int out_size, void* d_ws, size_t ws_size,
                              hipStream_t stream) {
    const float* features = (const float*)d_in[0];
    const int*   src      = (const int*)d_in[1];
    const int*   dst      = (const int*)d_in[2];
    const float* W1       = (const float*)d_in[3];
    const float* b1       = (const float*)d_in[4];
    const float* W2       = (const float*)d_in[5];
    const float* b2       = (const float*)d_in[6];
    float* out = (float*)d_out;

    const int N = in_sizes[0] / DIM;
    const int E = in_sizes[1];
    const int B = (N + 255) / 256;
    const int W2w = (N + 1) >> 1;                 // packed histogram words
    const int slice = (E + HB - 1) / HB;

    // workspace carve-up
    size_t nodeb = align_up((size_t)N * 4, 256);
    char* p = (char*)d_ws;
    int*   deg_out  = (int*)p;                      p += nodeb;
    int*   cnt      = (int*)p;                      p += nodeb;
    float* norm_src = (float*)p;                    p += nodeb;
    float* norm_dst = (float*)p;                    p += nodeb;
    int*   row_off  = (int*)p;                      p += align_up((size_t)(N + 1) * 4, 256);
    int*   bsum     = (int*)p;                      p += align_up((size_t)B * 4, 256);
    int*   bpre     = (int*)p;                      p += align_up((size_t)B * 4, 256);
    int*   csr_src  = (int*)p;                      p += align_up((size_t)E * 4, 256);
    float* scratch  = (float*)p;                    p += (size_t)N * DIM * 4;  // graph-build aliases
    float* h1       = (float*)p;                    p += (size_t)N * DIM * 4;
    // aliases over scratch+h1 (51.2 MB, all dead before layer-1 writes h1):
    char* ap = (char*)scratch;
    unsigned short* local = (unsigned short*)ap;    ap += align_up((size_t)E * 2, 256);
    unsigned* hist_in  = (unsigned*)ap;             ap += (size_t)HB * W2w * 4;
    unsigned* hist_out = (unsigned*)ap;             ap += (size_t)HB * W2w * 4;
    unsigned* aux_in   = (unsigned*)ap;             ap += (size_t)NCH * W2w * 4;
    unsigned* aux_out  = (unsigned*)ap;             ap += (size_t)NCH * W2w * 4;
    int* local_fb = (int*)scratch;                  // fallback path only

    const int edge_blocks = (E + 255) / 256;
    const int fuse_blocks = (N + GTM - 1) / GTM;
    const int cs_blocks   = (W2w + 255) / 256;

    const bool fast = (W2w <= HWORDS) &&
        (align_up((size_t)E * 2, 256) + (2 * (size_t)HB + 2 * NCH) * W2w * 4
            <= 2 * (size_t)N * DIM * 4);

    if (fast) {
        k_hist<<<HB, 256, 0, stream>>>(src, dst, local, hist_in, hist_out, E, W2w, slice);
        k_colscan1<<<dim3(cs_blocks, NCH), 256, 0, stream>>>(hist_in, hist_out, aux_in, aux_out, W2w);
        k_colscan2<<<cs_blocks, 256, 0, stream>>>(aux_in, aux_out, cnt, deg_out, W2w, N);
        k_block_reduce<<<B, 256, 0, stream>>>(cnt, bsum, N);
        k_scan_small<<<1, 256, 0, stream>>>(bsum, bpre, B);
        k_scan_final<<<B, 256, 0, stream>>>(cnt, deg_out, bpre, row_off, norm_src, norm_dst, N);
        k_fill<<<edge_blocks, 256, 0, stream>>>(src, dst, row_off, local, (const int*)nullptr,
                                                hist_in, aux_in, csr_src, E, W2w, slice);
    } else {
        hipMemsetAsync(deg_out, 0, nodeb * 2, stream);
        k_edge_pass_fb<<<edge_blocks, 256, 0, stream>>>(src, dst, deg_out, cnt, local_fb, E);
        k_block_reduce<<<B, 256, 0, stream>>>(cnt, bsum, N);
        k_scan_small<<<1, 256, 0, stream>>>(bsum, bpre, B);
        k_scan_final<<<B, 256, 0, stream>>>(cnt, deg_out, bpre, row_off, norm_src, norm_dst, N);
        k_fill<<<edge_blocks, 256, 0, stream>>>(src, dst, row_off, (const unsigned short*)nullptr,
                                                local_fb, (const unsigned*)nullptr, (const unsigned*)nullptr,
                                                csr_src, E, W2w, slice);
    }

    // layer 1: gather features (scaled by norm_src), GEMM W1, epilogue pre-scales h1 by norm_src
    k_spmm_gemm<<<fuse_blocks, 256, 0, stream>>>(features, csr_src, row_off, norm_src, norm_dst,
                                                 W1, b1, norm_src, h1, N);
    // layer 2: h1 already carries norm_src; final output unscaled
    k_spmm_gemm<<<fuse_blocks, 256, 0, stream>>>(h1, csr_src, row_off, (const float*)nullptr, norm_dst,
                                                 W2, b2, (const float*)nullptr, out, N);
}

// Round 10
// 272.256 us; speedup vs baseline: 1.1877x; 1.1877x over previous
//
#include <hip/hip_runtime.h>

#define DIM 128      // feature dim, fixed per reference
#define GTM 32       // gemm tile rows
#define NCH 8        // colscan chunks
#define CH  30       // copies per chunk
#define HB  (NCH*CH) // 240 histogram copies ~= CU count (1 block/CU, 100KB LDS)
#define HWORDS 25088 // max (N+1)/2 supported by LDS histogram (100,352 B)

// bf16 helpers: RNE float->bf16, exact bf16->float
static __device__ __forceinline__ unsigned short f2bf(float f) {
    unsigned u = __float_as_uint(f);
    u += 0x7fffu + ((u >> 16) & 1u);
    return (unsigned short)(u >> 16);
}
static __device__ __forceinline__ float bf2f(unsigned short b) {
    return __uint_as_float((unsigned)b << 16);
}

// ---------------- LDS-privatized dual histogram + rank capture ----------------
__global__ __launch_bounds__(256) void k_hist(const int* __restrict__ src,
                                              const int* __restrict__ dst,
                                              unsigned short* __restrict__ local,
                                              unsigned* __restrict__ hist_in,
                                              unsigned* __restrict__ hist_out,
                                              int E, int W2, int slice) {
    __shared__ unsigned h[HWORDS];
    const int t = threadIdx.x;
    const int b = blockIdx.x;
    const int e0 = b * slice;
    const int e1 = min(e0 + slice, E);

    for (int w = t; w < W2; w += 256) h[w] = 0u;
    __syncthreads();
    for (int e = e0 + t; e < e1; e += 256) {
        int d = dst[e];
        unsigned sh = (unsigned)(d & 1) * 16u;
        unsigned old = atomicAdd(&h[d >> 1], 1u << sh);
        local[e] = (unsigned short)((old >> sh) & 0xffffu);
    }
    __syncthreads();
    unsigned* oin = hist_in + (size_t)b * W2;
    for (int w = t; w < W2; w += 256) { oin[w] = h[w]; h[w] = 0u; }
    __syncthreads();
    for (int e = e0 + t; e < e1; e += 256) {
        int s = src[e];
        atomicAdd(&h[s >> 1], 1u << ((unsigned)(s & 1) * 16u));
    }
    __syncthreads();
    unsigned* oout = hist_out + (size_t)b * W2;
    for (int w = t; w < W2; w += 256) oout[w] = h[w];
}

// ---------------- colscan pass 1: in-chunk exclusive prefix + chunk totals ----------------
__global__ __launch_bounds__(256) void k_colscan1(unsigned* __restrict__ hist_in,
                                                  const unsigned* __restrict__ hist_out,
                                                  unsigned* __restrict__ aux_in,
                                                  unsigned* __restrict__ aux_out, int W2) {
    int w = blockIdx.x * 256 + threadIdx.x;
    if (w >= W2) return;
    int ch = blockIdx.y;
    size_t base = (size_t)ch * CH * W2 + w;
    unsigned run = 0;
    #pragma unroll 5
    for (int b = 0; b < CH; ++b) {
        unsigned* p = hist_in + base + (size_t)b * W2;
        unsigned x = *p;
        *p = run;          // in-chunk exclusive packed prefix
        run += x;          // halves independent (each < 65536)
    }
    aux_in[(size_t)ch * W2 + w] = run;
    unsigned run2 = 0;
    #pragma unroll 5
    for (int b = 0; b < CH; ++b) run2 += hist_out[base + (size_t)b * W2];
    aux_out[(size_t)ch * W2 + w] = run2;
}

// ---------------- colscan pass 2: scan chunk totals; totals -> cnt/deg_out ----------------
__global__ __launch_bounds__(256) void k_colscan2(unsigned* __restrict__ aux_in,
                                                  const unsigned* __restrict__ aux_out,
                                                  int* __restrict__ cnt,
                                                  int* __restrict__ deg_out,
                                                  int W2, int N) {
    int w = blockIdx.x * 256 + threadIdx.x;
    if (w >= W2) return;
    unsigned run = 0, run2 = 0;
    #pragma unroll
    for (int ch = 0; ch < NCH; ++ch) {
        unsigned x = aux_in[(size_t)ch * W2 + w];
        aux_in[(size_t)ch * W2 + w] = run;   // chunk base
        run += x;
        run2 += aux_out[(size_t)ch * W2 + w];
    }
    int n0 = w * 2, n1 = n0 + 1;
    cnt[n0] = (int)(run & 0xffffu);
    deg_out[n0] = (int)(run2 & 0xffffu);
    if (n1 < N) {
        cnt[n1] = (int)(run >> 16);
        deg_out[n1] = (int)(run2 >> 16);
    }
}

// ---------------- fallback edge pass (global atomics) for oversized N ----------------
__global__ __launch_bounds__(256) void k_edge_pass_fb(const int* __restrict__ src,
                                                      const int* __restrict__ dst,
                                                      int* __restrict__ deg_out,
                                                      int* __restrict__ cnt,
                                                      int* __restrict__ local_fb, int E) {
    int e = blockIdx.x * 256 + threadIdx.x;
    if (e < E) {
        atomicAdd(&deg_out[src[e]], 1);
        local_fb[e] = atomicAdd(&cnt[dst[e]], 1);
    }
}

// ---------------- scan step 1: per-block sums of cnt ----------------
__global__ __launch_bounds__(256) void k_block_reduce(const int* __restrict__ deg,
                                                      int* __restrict__ bsum, int N) {
    __shared__ int wsum[4];
    int i = blockIdx.x * 256 + threadIdx.x;
    int x = (i < N) ? deg[i] : 0;
    #pragma unroll
    for (int off = 32; off > 0; off >>= 1) x += __shfl_down(x, off, 64);
    int lane = threadIdx.x & 63, wave = threadIdx.x >> 6;
    if (lane == 0) wsum[wave] = x;
    __syncthreads();
    if (threadIdx.x == 0) bsum[blockIdx.x] = wsum[0] + wsum[1] + wsum[2] + wsum[3];
}

// ---------------- scan step 2: exclusive scan of block sums (1 block) ----------------
__global__ __launch_bounds__(256) void k_scan_small(const int* __restrict__ bsum,
                                                    int* __restrict__ bpre, int B) {
    __shared__ int wsum[4];
    __shared__ int carry_s;
    if (threadIdx.x == 0) carry_s = 0;
    __syncthreads();
    int lane = threadIdx.x & 63, wave = threadIdx.x >> 6;
    for (int base = 0; base < B; base += 256) {
        int i = base + threadIdx.x;
        int x = (i < B) ? bsum[i] : 0;
        int orig = x;
        #pragma unroll
        for (int off = 1; off < 64; off <<= 1) {
            int y = __shfl_up(x, off, 64);
            if (lane >= off) x += y;
        }
        if (lane == 63) wsum[wave] = x;
        __syncthreads();
        if (threadIdx.x == 0) {
            int s = 0;
            for (int w = 0; w < 4; ++w) { int t = wsum[w]; wsum[w] = s; s += t; }
        }
        __syncthreads();
        x += wsum[wave] + carry_s;
        if (i < B) bpre[i] = x - orig;
        __syncthreads();
        if (threadIdx.x == 255) carry_s = x;
        __syncthreads();
    }
}

// ---------------- scan step 3: row_off + both norms (fused) ----------------
__global__ __launch_bounds__(256) void k_scan_final(const int* __restrict__ cnt,
                                                    const int* __restrict__ deg_out,
                                                    const int* __restrict__ bpre,
                                                    int* __restrict__ row_off,
                                                    float* __restrict__ norm_src,
                                                    float* __restrict__ norm_dst, int N) {
    __shared__ int wsum[4];
    int i = blockIdx.x * 256 + threadIdx.x;
    int x = (i < N) ? cnt[i] : 0;
    int orig = x;
    int lane = threadIdx.x & 63, wave = threadIdx.x >> 6;
    #pragma unroll
    for (int off = 1; off < 64; off <<= 1) {
        int y = __shfl_up(x, off, 64);
        if (lane >= off) x += y;
    }
    if (lane == 63) wsum[wave] = x;
    __syncthreads();
    if (threadIdx.x == 0) {
        int s = 0;
        for (int w = 0; w < 4; ++w) { int t = wsum[w]; wsum[w] = s; s += t; }
    }
    __syncthreads();
    x += wsum[wave] + bpre[blockIdx.x];
    if (i < N) {
        row_off[i] = x - orig;
        int di = orig < 1 ? 1 : orig;
        norm_dst[i] = rsqrtf((float)di);
        int dov = deg_out[i]; if (dov < 1) dov = 1;
        norm_src[i] = rsqrtf((float)dov);
    }
    if (i == N - 1) row_off[N] = x;
}

// ---------------- CSR fill: pure scatter, no atomics ----------------
__global__ __launch_bounds__(256) void k_fill(const int* __restrict__ src,
                                              const int* __restrict__ dst,
                                              const int* __restrict__ row_off,
                                              const unsigned short* __restrict__ local,
                                              const int* __restrict__ local_fb,
                                              const unsigned* __restrict__ hist_in,
                                              const unsigned* __restrict__ aux_in,
                                              int* __restrict__ csr_src,
                                              int E, int W2, int slice) {
    int e = blockIdx.x * 256 + threadIdx.x;
    if (e < E) {
        int d = dst[e];
        int pos = row_off[d];
        if (hist_in) {
            int b = e / slice;
            int ch = b / CH;
            unsigned sh = (unsigned)(d & 1) * 16u;
            unsigned bo = (hist_in[(size_t)b * W2 + (d >> 1)] >> sh) & 0xffffu;
            unsigned cb = (aux_in[(size_t)ch * W2 + (d >> 1)] >> sh) & 0xffffu;
            pos += (int)bo + (int)cb + (int)local[e];
        } else {
            pos += local_fb[e];
        }
        csr_src[pos] = src[e];
    }
}

// ---------------- cast fp32 -> bf16 (RNE), streaming ----------------
__global__ __launch_bounds__(256) void k_cast(const float* __restrict__ in,
                                              unsigned short* __restrict__ out, int n4) {
    int i = blockIdx.x * 256 + threadIdx.x;
    if (i < n4) {
        float4 v = ((const float4*)in)[i];
        ushort4 o;
        o.x = f2bf(v.x); o.y = f2bf(v.y); o.z = f2bf(v.z); o.w = f2bf(v.w);
        ((ushort4*)out)[i] = o;
    }
}

// ---------------- CSR SpMM over bf16 rows: agg[d] = nd[d] * sum_s w(s)*h[s] ----------------
// 32 lanes per node, ushort4 (4 bf16, 8B) per lane -> 256B/row gather; fp32 accumulate.
__global__ __launch_bounds__(256) void k_spmm(const unsigned short* __restrict__ hb,
                                              const int* __restrict__ csr_src,
                                              const int* __restrict__ row_off,
                                              const float* __restrict__ norm_src,
                                              const float* __restrict__ norm_dst,
                                              float* __restrict__ agg, int N) {
    int t = blockIdx.x * 256 + threadIdx.x;
    int node = t >> 5;
    int lane = t & 31;
    if (node >= N) return;
    int beg = row_off[node], end = row_off[node + 1];
    float4 acc0 = make_float4(0.f, 0.f, 0.f, 0.f);
    float4 acc1 = make_float4(0.f, 0.f, 0.f, 0.f);
    int i = beg;
    if (norm_src) {
        for (; i + 4 <= end; i += 4) {
            int s0 = csr_src[i], s1 = csr_src[i + 1], s2 = csr_src[i + 2], s3 = csr_src[i + 3];
            float n0 = norm_src[s0], n1 = norm_src[s1], n2 = norm_src[s2], n3 = norm_src[s3];
            ushort4 u0 = *((const ushort4*)(hb + (size_t)s0 * DIM) + lane);
            ushort4 u1 = *((const ushort4*)(hb + (size_t)s1 * DIM) + lane);
            ushort4 u2 = *((const ushort4*)(hb + (size_t)s2 * DIM) + lane);
            ushort4 u3 = *((const ushort4*)(hb + (size_t)s3 * DIM) + lane);
            acc0.x += bf2f(u0.x) * n0; acc0.y += bf2f(u0.y) * n0; acc0.z += bf2f(u0.z) * n0; acc0.w += bf2f(u0.w) * n0;
            acc1.x += bf2f(u1.x) * n1; acc1.y += bf2f(u1.y) * n1; acc1.z += bf2f(u1.z) * n1; acc1.w += bf2f(u1.w) * n1;
            acc0.x += bf2f(u2.x) * n2; acc0.y += bf2f(u2.y) * n2; acc0.z += bf2f(u2.z) * n2; acc0.w += bf2f(u2.w) * n2;
            acc1.x += bf2f(u3.x) * n3; acc1.y += bf2f(u3.y) * n3; acc1.z += bf2f(u3.z) * n3; acc1.w += bf2f(u3.w) * n3;
        }
        for (; i < end; ++i) {
            int s0 = csr_src[i];
            float n0 = norm_src[s0];
            ushort4 u0 = *((const ushort4*)(hb + (size_t)s0 * DIM) + lane);
            acc0.x += bf2f(u0.x) * n0; acc0.y += bf2f(u0.y) * n0; acc0.z += bf2f(u0.z) * n0; acc0.w += bf2f(u0.w) * n0;
        }
    } else {
        for (; i + 4 <= end; i += 4) {
            int s0 = csr_src[i], s1 = csr_src[i + 1], s2 = csr_src[i + 2], s3 = csr_src[i + 3];
            ushort4 u0 = *((const ushort4*)(hb + (size_t)s0 * DIM) + lane);
            ushort4 u1 = *((const ushort4*)(hb + (size_t)s1 * DIM) + lane);
            ushort4 u2 = *((const ushort4*)(hb + (size_t)s2 * DIM) + lane);
            ushort4 u3 = *((const ushort4*)(hb + (size_t)s3 * DIM) + lane);
            acc0.x += bf2f(u0.x); acc0.y += bf2f(u0.y); acc0.z += bf2f(u0.z); acc0.w += bf2f(u0.w);
            acc1.x += bf2f(u1.x); acc1.y += bf2f(u1.y); acc1.z += bf2f(u1.z); acc1.w += bf2f(u1.w);
            acc0.x += bf2f(u2.x); acc0.y += bf2f(u2.y); acc0.z += bf2f(u2.z); acc0.w += bf2f(u2.w);
            acc1.x += bf2f(u3.x); acc1.y += bf2f(u3.y); acc1.z += bf2f(u3.z); acc1.w += bf2f(u3.w);
        }
        for (; i < end; ++i) {
            int s0 = csr_src[i];
            ushort4 u0 = *((const ushort4*)(hb + (size_t)s0 * DIM) + lane);
            acc0.x += bf2f(u0.x); acc0.y += bf2f(u0.y); acc0.z += bf2f(u0.z); acc0.w += bf2f(u0.w);
        }
    }
    float nd = norm_dst[node];
    float4 o;
    o.x = (acc0.x + acc1.x) * nd;
    o.y = (acc0.y + acc1.y) * nd;
    o.z = (acc0.z + acc1.z) * nd;
    o.w = (acc0.w + acc1.w) * nd;
    *((float4*)(agg + (size_t)node * DIM) + lane) = o;
}

// ---------------- fused GEMM: relu(agg @ W + b), fp32 or [postscale ⊙] bf16 out ----------------
// 32x128 tile, 256 threads, 4x4 acc/thread; full W in LDS; 72.7 KB -> 2 blocks/CU.
__global__ __launch_bounds__(256, 2) void k_gemm_bias_relu(
        const float* __restrict__ A, const float* __restrict__ W,
        const float* __restrict__ bias, const float* __restrict__ postscale,
        float* __restrict__ outf, unsigned short* __restrict__ outbf, int N) {
    __shared__ float Ws[DIM * DIM];   // [k][c] 64 KB
    __shared__ float As[GTM * 68];    // [r][64-k chunk], stride 68

    const int t = threadIdx.x;
    const int row0 = blockIdx.x * GTM;

    #pragma unroll
    for (int i = 0; i < 16; ++i) {
        int idx = (t + i * 256) * 4;
        *(float4*)(Ws + idx) = *(const float4*)(W + idx);
    }

    const int tx = t & 31;    // col group -> cols tx*4..+3
    const int ty = t >> 5;    // row group -> rows ty*4..+3
    const int c0t = tx * 4;

    float acc[4][4];
    #pragma unroll
    for (int i = 0; i < 4; ++i)
        #pragma unroll
        for (int j = 0; j < 4; ++j) acc[i][j] = 0.f;

    for (int kt = 0; kt < DIM; kt += 64) {
        #pragma unroll
        for (int i = 0; i < 2; ++i) {
            int fidx = (t + i * 256) * 4;
            int r = fidx >> 6;
            int k = fidx & 63;
            int gr = row0 + r;
            float4 v = make_float4(0.f, 0.f, 0.f, 0.f);
            if (gr < N) v = *(const float4*)(A + (size_t)gr * DIM + kt + k);
            *(float4*)(As + r * 68 + k) = v;
        }
        __syncthreads();

        #pragma unroll 4
        for (int k = 0; k < 64; k += 4) {
            float a[4][4];
            float w[4][4];
            #pragma unroll
            for (int i = 0; i < 4; ++i)
                *(float4*)a[i] = *(const float4*)(As + (ty * 4 + i) * 68 + k);
            #pragma unroll
            for (int kk = 0; kk < 4; ++kk)
                *(float4*)w[kk] = *(const float4*)(Ws + (kt + k + kk) * DIM + c0t);
            #pragma unroll
            for (int kk = 0; kk < 4; ++kk)
                #pragma unroll
                for (int i = 0; i < 4; ++i)
                    #pragma unroll
                    for (int j = 0; j < 4; ++j)
                        acc[i][j] += a[i][kk] * w[kk][j];
        }
        __syncthreads();
    }

    float bb[4];
    #pragma unroll
    for (int j = 0; j < 4; ++j) bb[j] = bias[c0t + j];
    #pragma unroll
    for (int i = 0; i < 4; ++i) {
        int gr = row0 + ty * 4 + i;
        if (gr < N) {
            float s = postscale ? postscale[gr] : 1.f;
            float4 o;
            o.x = fmaxf(acc[i][0] + bb[0], 0.f) * s;
            o.y = fmaxf(acc[i][1] + bb[1], 0.f) * s;
            o.z = fmaxf(acc[i][2] + bb[2], 0.f) * s;
            o.w = fmaxf(acc[i][3] + bb[3], 0.f) * s;
            if (outbf) {
                ushort4 ob;
                ob.x = f2bf(o.x); ob.y = f2bf(o.y); ob.z = f2bf(o.z); ob.w = f2bf(o.w);
                *(ushort4*)(outbf + (size_t)gr * DIM + c0t) = ob;
            } else {
                *(float4*)(outf + (size_t)gr * DIM + c0t) = o;
            }
        }
    }
}

static inline size_t align_up(size_t x, size_t a) { return (x + a - 1) & ~(a - 1); }

extern "C" void kernel_launch(void* const* d_in, const int* in_sizes, int n_in,
                              void* d_out, int out_size, void* d_ws, size_t ws_size,
                              hipStream_t stream) {
    const float* features = (const float*)d_in[0];
    const int*   src      = (const int*)d_in[1];
    const int*   dst      = (const int*)d_in[2];
    const float* W1       = (const float*)d_in[3];
    const float* b1       = (const float*)d_in[4];
    const float* W2       = (const float*)d_in[5];
    const float* b2       = (const float*)d_in[6];
    float* out = (float*)d_out;

    const int N = in_sizes[0] / DIM;
    const int E = in_sizes[1];
    const int B = (N + 255) / 256;
    const int W2w = (N + 1) >> 1;                 // packed histogram words
    const int slice = (E + HB - 1) / HB;

    // workspace carve-up
    size_t nodeb = align_up((size_t)N * 4, 256);
    char* p = (char*)d_ws;
    int*   deg_out  = (int*)p;                      p += nodeb;
    int*   cnt      = (int*)p;                      p += nodeb;
    float* norm_src = (float*)p;                    p += nodeb;
    float* norm_dst = (float*)p;                    p += nodeb;
    int*   row_off  = (int*)p;                      p += align_up((size_t)(N + 1) * 4, 256);
    int*   bsum     = (int*)p;                      p += align_up((size_t)B * 4, 256);
    int*   bpre     = (int*)p;                      p += align_up((size_t)B * 4, 256);
    int*   csr_src  = (int*)p;                      p += align_up((size_t)E * 4, 256);
    float* agg      = (float*)p;                    p += (size_t)N * DIM * 4;   // 25.6 MB
    unsigned short* fbf  = (unsigned short*)p;      p += (size_t)N * DIM * 2;   // 12.8 MB
    unsigned short* h1bf = (unsigned short*)p;      p += (size_t)N * DIM * 2;   // 12.8 MB
    // graph-build aliases over [agg, fbf, h1bf] (51.2 MB, dead until after k_fill):
    char* ap = (char*)agg;
    unsigned short* local = (unsigned short*)ap;    ap += align_up((size_t)E * 2, 256);
    unsigned* hist_in  = (unsigned*)ap;             ap += (size_t)HB * W2w * 4;
    unsigned* hist_out = (unsigned*)ap;             ap += (size_t)HB * W2w * 4;
    unsigned* aux_in   = (unsigned*)ap;             ap += (size_t)NCH * W2w * 4;
    unsigned* aux_out  = (unsigned*)ap;             ap += (size_t)NCH * W2w * 4;
    int* local_fb = (int*)agg;                      // fallback path only

    const int edge_blocks = (E + 255) / 256;
    const int spmm_blocks = (int)(((size_t)N * 32 + 255) / 256);
    const int gemm_blocks = (N + GTM - 1) / GTM;
    const int cs_blocks   = (W2w + 255) / 256;
    const int n4 = N * (DIM / 4);
    const int cast_blocks = (n4 + 255) / 256;

    const bool fast = (W2w <= HWORDS) &&
        (align_up((size_t)E * 2, 256) + (2 * (size_t)HB + 2 * NCH) * W2w * 4
            <= 2 * (size_t)N * DIM * 4);

    if (fast) {
        k_hist<<<HB, 256, 0, stream>>>(src, dst, local, hist_in, hist_out, E, W2w, slice);
        k_colscan1<<<dim3(cs_blocks, NCH), 256, 0, stream>>>(hist_in, hist_out, aux_in, aux_out, W2w);
        k_colscan2<<<cs_blocks, 256, 0, stream>>>(aux_in, aux_out, cnt, deg_out, W2w, N);
        k_block_reduce<<<B, 256, 0, stream>>>(cnt, bsum, N);
        k_scan_small<<<1, 256, 0, stream>>>(bsum, bpre, B);
        k_scan_final<<<B, 256, 0, stream>>>(cnt, deg_out, bpre, row_off, norm_src, norm_dst, N);
        k_fill<<<edge_blocks, 256, 0, stream>>>(src, dst, row_off, local, (const int*)nullptr,
                                                hist_in, aux_in, csr_src, E, W2w, slice);
    } else {
        hipMemsetAsync(deg_out, 0, nodeb * 2, stream);
        k_edge_pass_fb<<<edge_blocks, 256, 0, stream>>>(src, dst, deg_out, cnt, local_fb, E);
        k_block_reduce<<<B, 256, 0, stream>>>(cnt, bsum, N);
        k_scan_small<<<1, 256, 0, stream>>>(bsum, bpre, B);
        k_scan_final<<<B, 256, 0, stream>>>(cnt, deg_out, bpre, row_off, norm_src, norm_dst, N);
        k_fill<<<edge_blocks, 256, 0, stream>>>(src, dst, row_off, (const unsigned short*)nullptr,
                                                local_fb, (const unsigned*)nullptr, (const unsigned*)nullptr,
                                                csr_src, E, W2w, slice);
    }

    // cast features to bf16 (after graph build: fbf aliases the histogram region)
    k_cast<<<cast_blocks, 256, 0, stream>>>(features, fbf, n4);

    // layer 1: bf16 gather (scaled by norm_src), fp32 GEMM W1; epilogue emits h1 as bf16
    // with norm_src pre-applied for layer 2
    k_spmm<<<spmm_blocks, 256, 0, stream>>>(fbf, csr_src, row_off, norm_src, norm_dst, agg, N);
    k_gemm_bias_relu<<<gemm_blocks, 256, 0, stream>>>(agg, W1, b1, norm_src,
                                                      (float*)nullptr, h1bf, N);

    // layer 2: bf16 gather of pre-scaled h1; final fp32 output
    k_spmm<<<spmm_blocks, 256, 0, stream>>>(h1bf, csr_src, row_off, (const float*)nullptr, norm_dst, agg, N);
    k_gemm_bias_relu<<<gemm_blocks, 256, 0, stream>>>(agg, W2, b2, (const float*)nullptr,
                                                      out, (unsigned short*)nullptr, N);
}

// Round 11
// 240.475 us; speedup vs baseline: 1.3447x; 1.1322x over previous
//
#include <hip/hip_runtime.h>

#define DIM 128      // feature dim, fixed per reference
#define NCH 8        // colscan chunks
#define CH  30       // copies per chunk
#define HB  (NCH*CH) // 240 histogram copies ~= CU count (1 block/CU, 100KB LDS)
#define HWORDS 25088 // max (N+1)/2 supported by LDS histogram (100,352 B)
#define WSTR 136     // LDS stride for W tiles (bf16 elems): 16B aligned, 2-way banks

typedef __attribute__((ext_vector_type(8))) short b8;   // 8 bf16 (4 VGPRs)
typedef __attribute__((ext_vector_type(4))) float f4;   // MFMA acc

// bf16 helpers: RNE float->bf16, exact bf16->float
static __device__ __forceinline__ unsigned short f2bf(float f) {
    unsigned u = __float_as_uint(f);
    u += 0x7fffu + ((u >> 16) & 1u);
    return (unsigned short)(u >> 16);
}
static __device__ __forceinline__ float bf2f(unsigned short b) {
    return __uint_as_float((unsigned)b << 16);
}

// ---------------- LDS-privatized dual histogram + rank capture ----------------
__global__ __launch_bounds__(256) void k_hist(const int* __restrict__ src,
                                              const int* __restrict__ dst,
                                              unsigned short* __restrict__ local,
                                              unsigned* __restrict__ hist_in,
                                              unsigned* __restrict__ hist_out,
                                              int E, int W2, int slice) {
    __shared__ unsigned h[HWORDS];
    const int t = threadIdx.x;
    const int b = blockIdx.x;
    const int e0 = b * slice;
    const int e1 = min(e0 + slice, E);

    for (int w = t; w < W2; w += 256) h[w] = 0u;
    __syncthreads();
    for (int e = e0 + t; e < e1; e += 256) {
        int d = dst[e];
        unsigned sh = (unsigned)(d & 1) * 16u;
        unsigned old = atomicAdd(&h[d >> 1], 1u << sh);
        local[e] = (unsigned short)((old >> sh) & 0xffffu);
    }
    __syncthreads();
    unsigned* oin = hist_in + (size_t)b * W2;
    for (int w = t; w < W2; w += 256) { oin[w] = h[w]; h[w] = 0u; }
    __syncthreads();
    for (int e = e0 + t; e < e1; e += 256) {
        int s = src[e];
        atomicAdd(&h[s >> 1], 1u << ((unsigned)(s & 1) * 16u));
    }
    __syncthreads();
    unsigned* oout = hist_out + (size_t)b * W2;
    for (int w = t; w < W2; w += 256) oout[w] = h[w];
}

// ---------------- colscan pass 1: in-chunk exclusive prefix + chunk totals ----------------
__global__ __launch_bounds__(256) void k_colscan1(unsigned* __restrict__ hist_in,
                                                  const unsigned* __restrict__ hist_out,
                                                  unsigned* __restrict__ aux_in,
                                                  unsigned* __restrict__ aux_out, int W2) {
    int w = blockIdx.x * 256 + threadIdx.x;
    if (w >= W2) return;
    int ch = blockIdx.y;
    size_t base = (size_t)ch * CH * W2 + w;
    unsigned run = 0;
    #pragma unroll 5
    for (int b = 0; b < CH; ++b) {
        unsigned* p = hist_in + base + (size_t)b * W2;
        unsigned x = *p;
        *p = run;          // in-chunk exclusive packed prefix
        run += x;          // halves independent (each < 65536)
    }
    aux_in[(size_t)ch * W2 + w] = run;
    unsigned run2 = 0;
    #pragma unroll 5
    for (int b = 0; b < CH; ++b) run2 += hist_out[base + (size_t)b * W2];
    aux_out[(size_t)ch * W2 + w] = run2;
}

// ---------------- colscan pass 2: scan chunk totals; totals -> cnt/deg_out ----------------
__global__ __launch_bounds__(256) void k_colscan2(unsigned* __restrict__ aux_in,
                                                  const unsigned* __restrict__ aux_out,
                                                  int* __restrict__ cnt,
                                                  int* __restrict__ deg_out,
                                                  int W2, int N) {
    int w = blockIdx.x * 256 + threadIdx.x;
    if (w >= W2) return;
    unsigned run = 0, run2 = 0;
    #pragma unroll
    for (int ch = 0; ch < NCH; ++ch) {
        unsigned x = aux_in[(size_t)ch * W2 + w];
        aux_in[(size_t)ch * W2 + w] = run;   // chunk base
        run += x;
        run2 += aux_out[(size_t)ch * W2 + w];
    }
    int n0 = w * 2, n1 = n0 + 1;
    cnt[n0] = (int)(run & 0xffffu);
    deg_out[n0] = (int)(run2 & 0xffffu);
    if (n1 < N) {
        cnt[n1] = (int)(run >> 16);
        deg_out[n1] = (int)(run2 >> 16);
    }
}

// ---------------- fallback edge pass (global atomics) for oversized N ----------------
__global__ __launch_bounds__(256) void k_edge_pass_fb(const int* __restrict__ src,
                                                      const int* __restrict__ dst,
                                                      int* __restrict__ deg_out,
                                                      int* __restrict__ cnt,
                                                      int* __restrict__ local_fb, int E) {
    int e = blockIdx.x * 256 + threadIdx.x;
    if (e < E) {
        atomicAdd(&deg_out[src[e]], 1);
        local_fb[e] = atomicAdd(&cnt[dst[e]], 1);
    }
}

// ---------------- scan step 1: per-block sums of cnt ----------------
__global__ __launch_bounds__(256) void k_block_reduce(const int* __restrict__ deg,
                                                      int* __restrict__ bsum, int N) {
    __shared__ int wsum[4];
    int i = blockIdx.x * 256 + threadIdx.x;
    int x = (i < N) ? deg[i] : 0;
    #pragma unroll
    for (int off = 32; off > 0; off >>= 1) x += __shfl_down(x, off, 64);
    int lane = threadIdx.x & 63, wave = threadIdx.x >> 6;
    if (lane == 0) wsum[wave] = x;
    __syncthreads();
    if (threadIdx.x == 0) bsum[blockIdx.x] = wsum[0] + wsum[1] + wsum[2] + wsum[3];
}

// ---------------- scan step 2: exclusive scan of block sums (1 block) ----------------
__global__ __launch_bounds__(256) void k_scan_small(const int* __restrict__ bsum,
                                                    int* __restrict__ bpre, int B) {
    __shared__ int wsum[4];
    __shared__ int carry_s;
    if (threadIdx.x == 0) carry_s = 0;
    __syncthreads();
    int lane = threadIdx.x & 63, wave = threadIdx.x >> 6;
    for (int base = 0; base < B; base += 256) {
        int i = base + threadIdx.x;
        int x = (i < B) ? bsum[i] : 0;
        int orig = x;
        #pragma unroll
        for (int off = 1; off < 64; off <<= 1) {
            int y = __shfl_up(x, off, 64);
            if (lane >= off) x += y;
        }
        if (lane == 63) wsum[wave] = x;
        __syncthreads();
        if (threadIdx.x == 0) {
            int s = 0;
            for (int w = 0; w < 4; ++w) { int t = wsum[w]; wsum[w] = s; s += t; }
        }
        __syncthreads();
        x += wsum[wave] + carry_s;
        if (i < B) bpre[i] = x - orig;
        __syncthreads();
        if (threadIdx.x == 255) carry_s = x;
        __syncthreads();
    }
}

// ---------------- scan step 3: row_off + both norms (fused) ----------------
__global__ __launch_bounds__(256) void k_scan_final(const int* __restrict__ cnt,
                                                    const int* __restrict__ deg_out,
                                                    const int* __restrict__ bpre,
                                                    int* __restrict__ row_off,
                                                    float* __restrict__ norm_src,
                                                    float* __restrict__ norm_dst, int N) {
    __shared__ int wsum[4];
    int i = blockIdx.x * 256 + threadIdx.x;
    int x = (i < N) ? cnt[i] : 0;
    int orig = x;
    int lane = threadIdx.x & 63, wave = threadIdx.x >> 6;
    #pragma unroll
    for (int off = 1; off < 64; off <<= 1) {
        int y = __shfl_up(x, off, 64);
        if (lane >= off) x += y;
    }
    if (lane == 63) wsum[wave] = x;
    __syncthreads();
    if (threadIdx.x == 0) {
        int s = 0;
        for (int w = 0; w < 4; ++w) { int t = wsum[w]; wsum[w] = s; s += t; }
    }
    __syncthreads();
    x += wsum[wave] + bpre[blockIdx.x];
    if (i < N) {
        row_off[i] = x - orig;
        int di = orig < 1 ? 1 : orig;
        norm_dst[i] = rsqrtf((float)di);
        int dov = deg_out[i]; if (dov < 1) dov = 1;
        norm_src[i] = rsqrtf((float)dov);
    }
    if (i == N - 1) row_off[N] = x;
}

// ---------------- CSR fill: pure scatter, no atomics ----------------
__global__ __launch_bounds__(256) void k_fill(const int* __restrict__ src,
                                              const int* __restrict__ dst,
                                              const int* __restrict__ row_off,
                                              const unsigned short* __restrict__ local,
                                              const int* __restrict__ local_fb,
                                              const unsigned* __restrict__ hist_in,
                                              const unsigned* __restrict__ aux_in,
                                              int* __restrict__ csr_src,
                                              int E, int W2, int slice) {
    int e = blockIdx.x * 256 + threadIdx.x;
    if (e < E) {
        int d = dst[e];
        int pos = row_off[d];
        if (hist_in) {
            int b = e / slice;
            int ch = b / CH;
            unsigned sh = (unsigned)(d & 1) * 16u;
            unsigned bo = (hist_in[(size_t)b * W2 + (d >> 1)] >> sh) & 0xffffu;
            unsigned cb = (aux_in[(size_t)ch * W2 + (d >> 1)] >> sh) & 0xffffu;
            pos += (int)bo + (int)cb + (int)local[e];
        } else {
            pos += local_fb[e];
        }
        csr_src[pos] = src[e];
    }
}

// ---------------- cast fp32 -> bf16 (RNE), streaming ----------------
__global__ __launch_bounds__(256) void k_cast(const float* __restrict__ in,
                                              unsigned short* __restrict__ out, int n4) {
    int i = blockIdx.x * 256 + threadIdx.x;
    if (i < n4) {
        float4 v = ((const float4*)in)[i];
        ushort4 o;
        o.x = f2bf(v.x); o.y = f2bf(v.y); o.z = f2bf(v.z); o.w = f2bf(v.w);
        ((ushort4*)out)[i] = o;
    }
}

// ---------------- prep: W[k][c] fp32 -> Wt_hi/Wt_lo[c][k] bf16 (hi/lo split) ----------------
__global__ __launch_bounds__(256) void k_prep(const float* __restrict__ W,
                                              unsigned short* __restrict__ Wt_hi,
                                              unsigned short* __restrict__ Wt_lo) {
    int e = blockIdx.x * 256 + threadIdx.x;   // 16384 elems
    if (e < DIM * DIM) {
        int k = e >> 7, c = e & 127;
        float w = W[e];
        unsigned short hi = f2bf(w);
        unsigned short lo = f2bf(w - bf2f(hi));
        Wt_hi[c * DIM + k] = hi;
        Wt_lo[c * DIM + k] = lo;
    }
}

// ---------------- CSR SpMM over bf16 rows -> bf16 agg ----------------
// 32 lanes per node, ushort4 (4 bf16) per lane; fp32 accumulate; bf16 out.
__global__ __launch_bounds__(256) void k_spmm(const unsigned short* __restrict__ hb,
                                              const int* __restrict__ csr_src,
                                              const int* __restrict__ row_off,
                                              const float* __restrict__ norm_src,
                                              const float* __restrict__ norm_dst,
                                              unsigned short* __restrict__ aggbf, int N) {
    int t = blockIdx.x * 256 + threadIdx.x;
    int node = t >> 5;
    int lane = t & 31;
    if (node >= N) return;
    int beg = row_off[node], end = row_off[node + 1];
    float4 acc0 = make_float4(0.f, 0.f, 0.f, 0.f);
    float4 acc1 = make_float4(0.f, 0.f, 0.f, 0.f);
    int i = beg;
    if (norm_src) {
        for (; i + 4 <= end; i += 4) {
            int s0 = csr_src[i], s1 = csr_src[i + 1], s2 = csr_src[i + 2], s3 = csr_src[i + 3];
            float n0 = norm_src[s0], n1 = norm_src[s1], n2 = norm_src[s2], n3 = norm_src[s3];
            ushort4 u0 = *((const ushort4*)(hb + (size_t)s0 * DIM) + lane);
            ushort4 u1 = *((const ushort4*)(hb + (size_t)s1 * DIM) + lane);
            ushort4 u2 = *((const ushort4*)(hb + (size_t)s2 * DIM) + lane);
            ushort4 u3 = *((const ushort4*)(hb + (size_t)s3 * DIM) + lane);
            acc0.x += bf2f(u0.x) * n0; acc0.y += bf2f(u0.y) * n0; acc0.z += bf2f(u0.z) * n0; acc0.w += bf2f(u0.w) * n0;
            acc1.x += bf2f(u1.x) * n1; acc1.y += bf2f(u1.y) * n1; acc1.z += bf2f(u1.z) * n1; acc1.w += bf2f(u1.w) * n1;
            acc0.x += bf2f(u2.x) * n2; acc0.y += bf2f(u2.y) * n2; acc0.z += bf2f(u2.z) * n2; acc0.w += bf2f(u2.w) * n2;
            acc1.x += bf2f(u3.x) * n3; acc1.y += bf2f(u3.y) * n3; acc1.z += bf2f(u3.z) * n3; acc1.w += bf2f(u3.w) * n3;
        }
        for (; i < end; ++i) {
            int s0 = csr_src[i];
            float n0 = norm_src[s0];
            ushort4 u0 = *((const ushort4*)(hb + (size_t)s0 * DIM) + lane);
            acc0.x += bf2f(u0.x) * n0; acc0.y += bf2f(u0.y) * n0; acc0.z += bf2f(u0.z) * n0; acc0.w += bf2f(u0.w) * n0;
        }
    } else {
        for (; i + 4 <= end; i += 4) {
            int s0 = csr_src[i], s1 = csr_src[i + 1], s2 = csr_src[i + 2], s3 = csr_src[i + 3];
            ushort4 u0 = *((const ushort4*)(hb + (size_t)s0 * DIM) + lane);
            ushort4 u1 = *((const ushort4*)(hb + (size_t)s1 * DIM) + lane);
            ushort4 u2 = *((const ushort4*)(hb + (size_t)s2 * DIM) + lane);
            ushort4 u3 = *((const ushort4*)(hb + (size_t)s3 * DIM) + lane);
            acc0.x += bf2f(u0.x); acc0.y += bf2f(u0.y); acc0.z += bf2f(u0.z); acc0.w += bf2f(u0.w);
            acc1.x += bf2f(u1.x); acc1.y += bf2f(u1.y); acc1.z += bf2f(u1.z); acc1.w += bf2f(u1.w);
            acc0.x += bf2f(u2.x); acc0.y += bf2f(u2.y); acc0.z += bf2f(u2.z); acc0.w += bf2f(u2.w);
            acc1.x += bf2f(u3.x); acc1.y += bf2f(u3.y); acc1.z += bf2f(u3.z); acc1.w += bf2f(u3.w);
        }
        for (; i < end; ++i) {
            int s0 = csr_src[i];
            ushort4 u0 = *((const ushort4*)(hb + (size_t)s0 * DIM) + lane);
            acc0.x += bf2f(u0.x); acc0.y += bf2f(u0.y); acc0.z += bf2f(u0.z); acc0.w += bf2f(u0.w);
        }
    }
    float nd = norm_dst[node];
    ushort4 o;
    o.x = f2bf((acc0.x + acc1.x) * nd);
    o.y = f2bf((acc0.y + acc1.y) * nd);
    o.z = f2bf((acc0.z + acc1.z) * nd);
    o.w = f2bf((acc0.w + acc1.w) * nd);
    *((ushort4*)(aggbf + (size_t)node * DIM) + lane) = o;
}

// ---------------- MFMA GEMM: out = [ps ⊙] relu(Abf @ (Whi+Wlo) + b) ----------------
// 256 thr = 4 waves x 32 rows = 128 rows/block. W hi/lo in LDS ([c][k], stride 136,
// 68 KB -> 2 blocks/CU); A fragments streamed from global (16B/lane, A-layout
// m=lane&15, k=quad*8+j). C-layout col=lane&15, row=quad*4+reg -> 64B stores.
__global__ __launch_bounds__(256, 2) void k_gemm_mfma(
        const unsigned short* __restrict__ A,      // [N][128] bf16
        const unsigned short* __restrict__ Wt_hi,  // [c][k] bf16
        const unsigned short* __restrict__ Wt_lo,
        const float* __restrict__ bias,
        const float* __restrict__ postscale,       // null => none
        float* __restrict__ outf, unsigned short* __restrict__ outbf, int N) {
    __shared__ unsigned short WH[DIM * WSTR];
    __shared__ unsigned short WL[DIM * WSTR];

    const int t = threadIdx.x;
    // stage Wt hi/lo: 16384 bf16 each = 8 x 16B chunks per thread
    #pragma unroll
    for (int i = 0; i < 8; ++i) {
        int e = (t + i * 256) * 8;      // elem idx in [c][k] 128x128
        int c = e >> 7, k = e & 127;
        *(float4*)(WH + c * WSTR + k) = *(const float4*)(Wt_hi + e);
        *(float4*)(WL + c * WSTR + k) = *(const float4*)(Wt_lo + e);
    }
    __syncthreads();

    const int wv = t >> 6;
    const int l = t & 63;
    const int m = l & 15;
    const int quad = l >> 4;
    const int row_t0 = blockIdx.x * 128 + wv * 32;   // wave covers rows [row_t0, row_t0+32)

    f4 acc[2][8];
    #pragma unroll
    for (int rt = 0; rt < 2; ++rt)
        #pragma unroll
        for (int ct = 0; ct < 8; ++ct)
            acc[rt][ct] = (f4){0.f, 0.f, 0.f, 0.f};

    int r0 = row_t0 + m;      if (r0 >= N) r0 = N - 1;   // clamp; stores guarded
    int r1 = row_t0 + 16 + m; if (r1 >= N) r1 = N - 1;

    #pragma unroll
    for (int ks = 0; ks < 4; ++ks) {
        int koff = ks * 32 + quad * 8;
        b8 a0 = *(const b8*)(A + (size_t)r0 * DIM + koff);
        b8 a1 = *(const b8*)(A + (size_t)r1 * DIM + koff);
        #pragma unroll
        for (int ct = 0; ct < 8; ++ct) {
            int c = ct * 16 + m;
            b8 bh = *(const b8*)(WH + c * WSTR + koff);
            b8 bl = *(const b8*)(WL + c * WSTR + koff);
            acc[0][ct] = __builtin_amdgcn_mfma_f32_16x16x32_bf16(a0, bh, acc[0][ct], 0, 0, 0);
            acc[0][ct] = __builtin_amdgcn_mfma_f32_16x16x32_bf16(a0, bl, acc[0][ct], 0, 0, 0);
            acc[1][ct] = __builtin_amdgcn_mfma_f32_16x16x32_bf16(a1, bh, acc[1][ct], 0, 0, 0);
            acc[1][ct] = __builtin_amdgcn_mfma_f32_16x16x32_bf16(a1, bl, acc[1][ct], 0, 0, 0);
        }
    }

    // epilogue: bias + relu [+ postscale], guarded stores
    #pragma unroll
    for (int rt = 0; rt < 2; ++rt) {
        int rowb = row_t0 + rt * 16 + quad * 4;
        #pragma unroll
        for (int r = 0; r < 4; ++r) {
            int gr = rowb + r;
            if (gr < N) {
                float s = postscale ? postscale[gr] : 1.f;
                #pragma unroll
                for (int ct = 0; ct < 8; ++ct) {
                    int col = ct * 16 + m;
                    float v = fmaxf(acc[rt][ct][r] + bias[col], 0.f) * s;
                    if (outbf) outbf[(size_t)gr * DIM + col] = f2bf(v);
                    else       outf[(size_t)gr * DIM + col] = v;
                }
            }
        }
    }
}

static inline size_t align_up(size_t x, size_t a) { return (x + a - 1) & ~(a - 1); }

extern "C" void kernel_launch(void* const* d_in, const int* in_sizes, int n_in,
                              void* d_out, int out_size, void* d_ws, size_t ws_size,
                              hipStream_t stream) {
    const float* features = (const float*)d_in[0];
    const int*   src      = (const int*)d_in[1];
    const int*   dst      = (const int*)d_in[2];
    const float* W1       = (const float*)d_in[3];
    const float* b1       = (const float*)d_in[4];
    const float* W2       = (const float*)d_in[5];
    const float* b2       = (const float*)d_in[6];
    float* out = (float*)d_out;

    const int N = in_sizes[0] / DIM;
    const int E = in_sizes[1];
    const int B = (N + 255) / 256;
    const int W2w = (N + 1) >> 1;                 // packed histogram words
    const int slice = (E + HB - 1) / HB;

    // workspace carve-up
    size_t nodeb = align_up((size_t)N * 4, 256);
    char* p = (char*)d_ws;
    int*   deg_out  = (int*)p;                      p += nodeb;
    int*   cnt      = (int*)p;                      p += nodeb;
    float* norm_src = (float*)p;                    p += nodeb;
    float* norm_dst = (float*)p;                    p += nodeb;
    int*   row_off  = (int*)p;                      p += align_up((size_t)(N + 1) * 4, 256);
    int*   bsum     = (int*)p;                      p += align_up((size_t)B * 4, 256);
    int*   bpre     = (int*)p;                      p += align_up((size_t)B * 4, 256);
    int*   csr_src  = (int*)p;                      p += align_up((size_t)E * 4, 256);
    char*  big      = p;                            p += 2 * (size_t)N * DIM * 4;  // 51.2 MB region
    unsigned short* w1hi = (unsigned short*)p;      p += (size_t)DIM * DIM * 2;
    unsigned short* w1lo = (unsigned short*)p;      p += (size_t)DIM * DIM * 2;
    unsigned short* w2hi = (unsigned short*)p;      p += (size_t)DIM * DIM * 2;
    unsigned short* w2lo = (unsigned short*)p;      p += (size_t)DIM * DIM * 2;
    // steady-state layout inside big:
    unsigned short* aggbf = (unsigned short*)big;                       // 12.8 MB
    unsigned short* fbf   = (unsigned short*)(big + (size_t)N * DIM * 2);  // 12.8 MB
    unsigned short* h1bf  = (unsigned short*)(big + 2 * (size_t)N * DIM * 2); // 12.8 MB
    // graph-build aliases over big (dead before k_cast/k_spmm):
    char* ap = big;
    unsigned short* local = (unsigned short*)ap;    ap += align_up((size_t)E * 2, 256);
    unsigned* hist_in  = (unsigned*)ap;             ap += (size_t)HB * W2w * 4;
    unsigned* hist_out = (unsigned*)ap;             ap += (size_t)HB * W2w * 4;
    unsigned* aux_in   = (unsigned*)ap;             ap += (size_t)NCH * W2w * 4;
    unsigned* aux_out  = (unsigned*)ap;             ap += (size_t)NCH * W2w * 4;
    int* local_fb = (int*)big;                      // fallback path only

    const int edge_blocks = (E + 255) / 256;
    const int spmm_blocks = (int)(((size_t)N * 32 + 255) / 256);
    const int gemm_blocks = (N + 127) / 128;
    const int cs_blocks   = (W2w + 255) / 256;
    const int n4 = N * (DIM / 4);
    const int cast_blocks = (n4 + 255) / 256;
    const int prep_blocks = (DIM * DIM + 255) / 256;

    const bool fast = (W2w <= HWORDS) &&
        (align_up((size_t)E * 2, 256) + (2 * (size_t)HB + 2 * NCH) * W2w * 4
            <= 2 * (size_t)N * DIM * 4);

    // weight prep (independent of graph build; outside alias region)
    k_prep<<<prep_blocks, 256, 0, stream>>>(W1, w1hi, w1lo);
    k_prep<<<prep_blocks, 256, 0, stream>>>(W2, w2hi, w2lo);

    if (fast) {
        k_hist<<<HB, 256, 0, stream>>>(src, dst, local, hist_in, hist_out, E, W2w, slice);
        k_colscan1<<<dim3(cs_blocks, NCH), 256, 0, stream>>>(hist_in, hist_out, aux_in, aux_out, W2w);
        k_colscan2<<<cs_blocks, 256, 0, stream>>>(aux_in, aux_out, cnt, deg_out, W2w, N);
        k_block_reduce<<<B, 256, 0, stream>>>(cnt, bsum, N);
        k_scan_small<<<1, 256, 0, stream>>>(bsum, bpre, B);
        k_scan_final<<<B, 256, 0, stream>>>(cnt, deg_out, bpre, row_off, norm_src, norm_dst, N);
        k_fill<<<edge_blocks, 256, 0, stream>>>(src, dst, row_off, local, (const int*)nullptr,
                                                hist_in, aux_in, csr_src, E, W2w, slice);
    } else {
        hipMemsetAsync(deg_out, 0, nodeb * 2, stream);
        k_edge_pass_fb<<<edge_blocks, 256, 0, stream>>>(src, dst, deg_out, cnt, local_fb, E);
        k_block_reduce<<<B, 256, 0, stream>>>(cnt, bsum, N);
        k_scan_small<<<1, 256, 0, stream>>>(bsum, bpre, B);
        k_scan_final<<<B, 256, 0, stream>>>(cnt, deg_out, bpre, row_off, norm_src, norm_dst, N);
        k_fill<<<edge_blocks, 256, 0, stream>>>(src, dst, row_off, (const unsigned short*)nullptr,
                                                local_fb, (const unsigned*)nullptr, (const unsigned*)nullptr,
                                                csr_src, E, W2w, slice);
    }

    // cast features to bf16 (after graph build: fbf aliases the histogram region)
    k_cast<<<cast_blocks, 256, 0, stream>>>(features, fbf, n4);

    // layer 1: bf16 gather (scaled by norm_src) -> aggbf; MFMA GEMM W1 -> h1bf
    // (epilogue pre-applies norm_src for layer 2)
    k_spmm<<<spmm_blocks, 256, 0, stream>>>(fbf, csr_src, row_off, norm_src, norm_dst, aggbf, N);
    k_gemm_mfma<<<gemm_blocks, 256, 0, stream>>>(aggbf, w1hi, w1lo, b1, norm_src,
                                                 (float*)nullptr, h1bf, N);

    // layer 2: bf16 gather of pre-scaled h1 -> aggbf; MFMA GEMM W2 -> out (fp32)
    k_spmm<<<spmm_blocks, 256, 0, stream>>>(h1bf, csr_src, row_off, (const float*)nullptr, norm_dst, aggbf, N);
    k_gemm_mfma<<<gemm_blocks, 256, 0, stream>>>(aggbf, w2hi, w2lo, b2, (const float*)nullptr,
                                                 out, (unsigned short*)nullptr, N);
}

// Round 12
// 231.839 us; speedup vs baseline: 1.3948x; 1.0373x over previous
//
#include <hip/hip_runtime.h>

#define DIM 128      // feature dim, fixed per reference
#define NCH 8        // colscan chunks
#define CH  22       // copies per chunk
#define HB  (NCH*CH) // 176 histogram copies (1 block/CU, 100KB LDS); frees tail for fbf
#define HWORDS 25088 // max (N+1)/2 supported by LDS histogram (100,352 B)
#define WSTR 136     // LDS stride for W tiles (bf16 elems): 16B aligned, 2-way banks

typedef __attribute__((ext_vector_type(8))) short b8;   // 8 bf16 (4 VGPRs)
typedef __attribute__((ext_vector_type(4))) float f4;   // MFMA acc

// bf16 helpers: RNE float->bf16, exact bf16->float
static __device__ __forceinline__ unsigned short f2bf(float f) {
    unsigned u = __float_as_uint(f);
    u += 0x7fffu + ((u >> 16) & 1u);
    return (unsigned short)(u >> 16);
}
static __device__ __forceinline__ float bf2f(unsigned short b) {
    return __uint_as_float((unsigned)b << 16);
}

// ---------------- LDS-privatized dual histogram + rank capture ----------------
__global__ __launch_bounds__(256) void k_hist(const int* __restrict__ src,
                                              const int* __restrict__ dst,
                                              unsigned short* __restrict__ local,
                                              unsigned* __restrict__ hist_in,
                                              unsigned* __restrict__ hist_out,
                                              int E, int W2, int slice) {
    __shared__ unsigned h[HWORDS];
    const int t = threadIdx.x;
    const int b = blockIdx.x;
    const int e0 = b * slice;
    const int e1 = min(e0 + slice, E);

    for (int w = t; w < W2; w += 256) h[w] = 0u;
    __syncthreads();
    for (int e = e0 + t; e < e1; e += 256) {
        int d = dst[e];
        unsigned sh = (unsigned)(d & 1) * 16u;
        unsigned old = atomicAdd(&h[d >> 1], 1u << sh);
        local[e] = (unsigned short)((old >> sh) & 0xffffu);
    }
    __syncthreads();
    unsigned* oin = hist_in + (size_t)b * W2;
    for (int w = t; w < W2; w += 256) { oin[w] = h[w]; h[w] = 0u; }
    __syncthreads();
    for (int e = e0 + t; e < e1; e += 256) {
        int s = src[e];
        atomicAdd(&h[s >> 1], 1u << ((unsigned)(s & 1) * 16u));
    }
    __syncthreads();
    unsigned* oout = hist_out + (size_t)b * W2;
    for (int w = t; w < W2; w += 256) oout[w] = h[w];
}

// ---------------- colscan pass 1: in-chunk exclusive prefix + chunk totals ----------------
__global__ __launch_bounds__(256) void k_colscan1(unsigned* __restrict__ hist_in,
                                                  const unsigned* __restrict__ hist_out,
                                                  unsigned* __restrict__ aux_in,
                                                  unsigned* __restrict__ aux_out, int W2) {
    int w = blockIdx.x * 256 + threadIdx.x;
    if (w >= W2) return;
    int ch = blockIdx.y;
    size_t base = (size_t)ch * CH * W2 + w;
    unsigned run = 0;
    #pragma unroll
    for (int b = 0; b < CH; ++b) {
        unsigned* p = hist_in + base + (size_t)b * W2;
        unsigned x = *p;
        *p = run;          // in-chunk exclusive packed prefix
        run += x;          // halves independent (each < 65536)
    }
    aux_in[(size_t)ch * W2 + w] = run;
    unsigned run2 = 0;
    #pragma unroll
    for (int b = 0; b < CH; ++b) run2 += hist_out[base + (size_t)b * W2];
    aux_out[(size_t)ch * W2 + w] = run2;
}

// ---------------- colscan pass 2 + fused block-reduce ----------------
// Scans chunk totals -> chunk bases; totals -> cnt/deg_out; ALSO reduces cnt
// into bsum: block covers 512 nodes = 2 bsum entries (waves 0-1 / 2-3).
__global__ __launch_bounds__(256) void k_colscan2(unsigned* __restrict__ aux_in,
                                                  const unsigned* __restrict__ aux_out,
                                                  int* __restrict__ cnt,
                                                  int* __restrict__ deg_out,
                                                  int* __restrict__ bsum,
                                                  int W2, int N) {
    __shared__ int wsum[4];
    int w = blockIdx.x * 256 + threadIdx.x;
    unsigned run = 0, run2 = 0;
    if (w < W2) {
        #pragma unroll
        for (int ch = 0; ch < NCH; ++ch) {
            unsigned x = aux_in[(size_t)ch * W2 + w];
            aux_in[(size_t)ch * W2 + w] = run;   // chunk base
            run += x;
            run2 += aux_out[(size_t)ch * W2 + w];
        }
        int n0 = w * 2, n1 = n0 + 1;
        cnt[n0] = (int)(run & 0xffffu);
        deg_out[n0] = (int)(run2 & 0xffffu);
        if (n1 < N) {
            cnt[n1] = (int)(run >> 16);
            deg_out[n1] = (int)(run2 >> 16);
        } else {
            run &= 0xffffu;   // exclude phantom high half from bsum
        }
    }
    // fused block-reduce of cnt (no early returns above: shuffles exec-safe)
    int tot = (int)(run & 0xffffu) + (int)(run >> 16);
    #pragma unroll
    for (int off = 32; off > 0; off >>= 1) tot += __shfl_down(tot, off, 64);
    int lane = threadIdx.x & 63, wave = threadIdx.x >> 6;
    if (lane == 0) wsum[wave] = tot;
    __syncthreads();
    if (threadIdx.x == 0)   bsum[2 * blockIdx.x]     = wsum[0] + wsum[1];
    if (threadIdx.x == 128) bsum[2 * blockIdx.x + 1] = wsum[2] + wsum[3];
}

// ---------------- fallback edge pass (global atomics) for oversized N ----------------
__global__ __launch_bounds__(256) void k_edge_pass_fb(const int* __restrict__ src,
                                                      const int* __restrict__ dst,
                                                      int* __restrict__ deg_out,
                                                      int* __restrict__ cnt,
                                                      int* __restrict__ local_fb, int E) {
    int e = blockIdx.x * 256 + threadIdx.x;
    if (e < E) {
        atomicAdd(&deg_out[src[e]], 1);
        local_fb[e] = atomicAdd(&cnt[dst[e]], 1);
    }
}

// ---------------- fallback block-reduce ----------------
__global__ __launch_bounds__(256) void k_block_reduce(const int* __restrict__ deg,
                                                      int* __restrict__ bsum, int N) {
    __shared__ int wsum[4];
    int i = blockIdx.x * 256 + threadIdx.x;
    int x = (i < N) ? deg[i] : 0;
    #pragma unroll
    for (int off = 32; off > 0; off >>= 1) x += __shfl_down(x, off, 64);
    int lane = threadIdx.x & 63, wave = threadIdx.x >> 6;
    if (lane == 0) wsum[wave] = x;
    __syncthreads();
    if (threadIdx.x == 0) bsum[blockIdx.x] = wsum[0] + wsum[1] + wsum[2] + wsum[3];
}

// ---------------- scan step 2: exclusive scan of block sums (1 block) ----------------
__global__ __launch_bounds__(256) void k_scan_small(const int* __restrict__ bsum,
                                                    int* __restrict__ bpre, int B) {
    __shared__ int wsum[4];
    __shared__ int carry_s;
    if (threadIdx.x == 0) carry_s = 0;
    __syncthreads();
    int lane = threadIdx.x & 63, wave = threadIdx.x >> 6;
    for (int base = 0; base < B; base += 256) {
        int i = base + threadIdx.x;
        int x = (i < B) ? bsum[i] : 0;
        int orig = x;
        #pragma unroll
        for (int off = 1; off < 64; off <<= 1) {
            int y = __shfl_up(x, off, 64);
            if (lane >= off) x += y;
        }
        if (lane == 63) wsum[wave] = x;
        __syncthreads();
        if (threadIdx.x == 0) {
            int s = 0;
            for (int w = 0; w < 4; ++w) { int t = wsum[w]; wsum[w] = s; s += t; }
        }
        __syncthreads();
        x += wsum[wave] + carry_s;
        if (i < B) bpre[i] = x - orig;
        __syncthreads();
        if (threadIdx.x == 255) carry_s = x;
        __syncthreads();
    }
}

// ---------------- scan step 3: row_off + both norms (fused) ----------------
__global__ __launch_bounds__(256) void k_scan_final(const int* __restrict__ cnt,
                                                    const int* __restrict__ deg_out,
                                                    const int* __restrict__ bpre,
                                                    int* __restrict__ row_off,
                                                    float* __restrict__ norm_src,
                                                    float* __restrict__ norm_dst, int N) {
    __shared__ int wsum[4];
    int i = blockIdx.x * 256 + threadIdx.x;
    int x = (i < N) ? cnt[i] : 0;
    int orig = x;
    int lane = threadIdx.x & 63, wave = threadIdx.x >> 6;
    #pragma unroll
    for (int off = 1; off < 64; off <<= 1) {
        int y = __shfl_up(x, off, 64);
        if (lane >= off) x += y;
    }
    if (lane == 63) wsum[wave] = x;
    __syncthreads();
    if (threadIdx.x == 0) {
        int s = 0;
        for (int w = 0; w < 4; ++w) { int t = wsum[w]; wsum[w] = s; s += t; }
    }
    __syncthreads();
    x += wsum[wave] + bpre[blockIdx.x];
    if (i < N) {
        row_off[i] = x - orig;
        int di = orig < 1 ? 1 : orig;
        norm_dst[i] = rsqrtf((float)di);
        int dov = deg_out[i]; if (dov < 1) dov = 1;
        norm_src[i] = rsqrtf((float)dov);
    }
    if (i == N - 1) row_off[N] = x;
}

// ---------------- fused CSR fill (atomic-free scatter) + feature cast ----------------
// blocks [0, eb): fill; blocks [eb, eb+cb): fp32->bf16 cast of features.
__global__ __launch_bounds__(256) void k_fill_cast(const int* __restrict__ src,
                                                   const int* __restrict__ dst,
                                                   const int* __restrict__ row_off,
                                                   const unsigned short* __restrict__ local,
                                                   const int* __restrict__ local_fb,
                                                   const unsigned* __restrict__ hist_in,
                                                   const unsigned* __restrict__ aux_in,
                                                   int* __restrict__ csr_src,
                                                   const float* __restrict__ feat,
                                                   unsigned short* __restrict__ fbf,
                                                   int E, int W2, int slice, int eb, int n4) {
    int bx = blockIdx.x;
    if (bx < eb) {
        int e = bx * 256 + threadIdx.x;
        if (e < E) {
            int d = dst[e];
            int pos = row_off[d];
            if (hist_in) {
                int b = e / slice;
                int ch = b / CH;
                unsigned sh = (unsigned)(d & 1) * 16u;
                unsigned bo = (hist_in[(size_t)b * W2 + (d >> 1)] >> sh) & 0xffffu;
                unsigned cb = (aux_in[(size_t)ch * W2 + (d >> 1)] >> sh) & 0xffffu;
                pos += (int)bo + (int)cb + (int)local[e];
            } else {
                pos += local_fb[e];
            }
            csr_src[pos] = src[e];
        }
    } else {
        int i = (bx - eb) * 256 + threadIdx.x;
        if (i < n4) {
            float4 v = ((const float4*)feat)[i];
            ushort4 o;
            o.x = f2bf(v.x); o.y = f2bf(v.y); o.z = f2bf(v.z); o.w = f2bf(v.w);
            ((ushort4*)fbf)[i] = o;
        }
    }
}

// ---------------- prep both weights: W[k][c] fp32 -> Wt_hi/Wt_lo[c][k] bf16 ----------------
__global__ __launch_bounds__(256) void k_prep(const float* __restrict__ W1,
                                              const float* __restrict__ W2,
                                              unsigned short* __restrict__ w1hi,
                                              unsigned short* __restrict__ w1lo,
                                              unsigned short* __restrict__ w2hi,
                                              unsigned short* __restrict__ w2lo, int pb) {
    int b = blockIdx.x;
    const float* W; unsigned short *Hi, *Lo;
    if (b < pb) { W = W1; Hi = w1hi; Lo = w1lo; } else { W = W2; Hi = w2hi; Lo = w2lo; b -= pb; }
    int e = b * 256 + threadIdx.x;   // 16384 elems
    if (e < DIM * DIM) {
        int k = e >> 7, c = e & 127;
        float w = W[e];
        unsigned short hi = f2bf(w);
        unsigned short lo = f2bf(w - bf2f(hi));
        Hi[c * DIM + k] = hi;
        Lo[c * DIM + k] = lo;
    }
}

// ---------------- CSR SpMM over bf16 rows -> bf16 agg ----------------
// 32 lanes per node, ushort4 (4 bf16) per lane; fp32 accumulate; bf16 out.
__global__ __launch_bounds__(256) void k_spmm(const unsigned short* __restrict__ hb,
                                              const int* __restrict__ csr_src,
                                              const int* __restrict__ row_off,
                                              const float* __restrict__ norm_src,
                                              const float* __restrict__ norm_dst,
                                              unsigned short* __restrict__ aggbf, int N) {
    int t = blockIdx.x * 256 + threadIdx.x;
    int node = t >> 5;
    int lane = t & 31;
    if (node >= N) return;
    int beg = row_off[node], end = row_off[node + 1];
    float4 acc0 = make_float4(0.f, 0.f, 0.f, 0.f);
    float4 acc1 = make_float4(0.f, 0.f, 0.f, 0.f);
    int i = beg;
    if (norm_src) {
        for (; i + 4 <= end; i += 4) {
            int s0 = csr_src[i], s1 = csr_src[i + 1], s2 = csr_src[i + 2], s3 = csr_src[i + 3];
            float n0 = norm_src[s0], n1 = norm_src[s1], n2 = norm_src[s2], n3 = norm_src[s3];
            ushort4 u0 = *((const ushort4*)(hb + (size_t)s0 * DIM) + lane);
            ushort4 u1 = *((const ushort4*)(hb + (size_t)s1 * DIM) + lane);
            ushort4 u2 = *((const ushort4*)(hb + (size_t)s2 * DIM) + lane);
            ushort4 u3 = *((const ushort4*)(hb + (size_t)s3 * DIM) + lane);
            acc0.x += bf2f(u0.x) * n0; acc0.y += bf2f(u0.y) * n0; acc0.z += bf2f(u0.z) * n0; acc0.w += bf2f(u0.w) * n0;
            acc1.x += bf2f(u1.x) * n1; acc1.y += bf2f(u1.y) * n1; acc1.z += bf2f(u1.z) * n1; acc1.w += bf2f(u1.w) * n1;
            acc0.x += bf2f(u2.x) * n2; acc0.y += bf2f(u2.y) * n2; acc0.z += bf2f(u2.z) * n2; acc0.w += bf2f(u2.w) * n2;
            acc1.x += bf2f(u3.x) * n3; acc1.y += bf2f(u3.y) * n3; acc1.z += bf2f(u3.z) * n3; acc1.w += bf2f(u3.w) * n3;
        }
        for (; i < end; ++i) {
            int s0 = csr_src[i];
            float n0 = norm_src[s0];
            ushort4 u0 = *((const ushort4*)(hb + (size_t)s0 * DIM) + lane);
            acc0.x += bf2f(u0.x) * n0; acc0.y += bf2f(u0.y) * n0; acc0.z += bf2f(u0.z) * n0; acc0.w += bf2f(u0.w) * n0;
        }
    } else {
        for (; i + 4 <= end; i += 4) {
            int s0 = csr_src[i], s1 = csr_src[i + 1], s2 = csr_src[i + 2], s3 = csr_src[i + 3];
            ushort4 u0 = *((const ushort4*)(hb + (size_t)s0 * DIM) + lane);
            ushort4 u1 = *((const ushort4*)(hb + (size_t)s1 * DIM) + lane);
            ushort4 u2 = *((const ushort4*)(hb + (size_t)s2 * DIM) + lane);
            ushort4 u3 = *((const ushort4*)(hb + (size_t)s3 * DIM) + lane);
            acc0.x += bf2f(u0.x); acc0.y += bf2f(u0.y); acc0.z += bf2f(u0.z); acc0.w += bf2f(u0.w);
            acc1.x += bf2f(u1.x); acc1.y += bf2f(u1.y); acc1.z += bf2f(u1.z); acc1.w += bf2f(u1.w);
            acc0.x += bf2f(u2.x); acc0.y += bf2f(u2.y); acc0.z += bf2f(u2.z); acc0.w += bf2f(u2.w);
            acc1.x += bf2f(u3.x); acc1.y += bf2f(u3.y); acc1.z += bf2f(u3.z); acc1.w += bf2f(u3.w);
        }
        for (; i < end; ++i) {
            int s0 = csr_src[i];
            ushort4 u0 = *((const ushort4*)(hb + (size_t)s0 * DIM) + lane);
            acc0.x += bf2f(u0.x); acc0.y += bf2f(u0.y); acc0.z += bf2f(u0.z); acc0.w += bf2f(u0.w);
        }
    }
    float nd = norm_dst[node];
    ushort4 o;
    o.x = f2bf((acc0.x + acc1.x) * nd);
    o.y = f2bf((acc0.y + acc1.y) * nd);
    o.z = f2bf((acc0.z + acc1.z) * nd);
    o.w = f2bf((acc0.w + acc1.w) * nd);
    *((ushort4*)(aggbf + (size_t)node * DIM) + lane) = o;
}

// ---------------- MFMA GEMM: out = [ps ⊙] relu(Abf @ (Whi+Wlo) + b) ----------------
__global__ __launch_bounds__(256, 2) void k_gemm_mfma(
        const unsigned short* __restrict__ A,      // [N][128] bf16
        const unsigned short* __restrict__ Wt_hi,  // [c][k] bf16
        const unsigned short* __restrict__ Wt_lo,
        const float* __restrict__ bias,
        const float* __restrict__ postscale,       // null => none
        float* __restrict__ outf, unsigned short* __restrict__ outbf, int N) {
    __shared__ unsigned short WH[DIM * WSTR];
    __shared__ unsigned short WL[DIM * WSTR];

    const int t = threadIdx.x;
    #pragma unroll
    for (int i = 0; i < 8; ++i) {
        int e = (t + i * 256) * 8;      // elem idx in [c][k] 128x128
        int c = e >> 7, k = e & 127;
        *(float4*)(WH + c * WSTR + k) = *(const float4*)(Wt_hi + e);
        *(float4*)(WL + c * WSTR + k) = *(const float4*)(Wt_lo + e);
    }
    __syncthreads();

    const int wv = t >> 6;
    const int l = t & 63;
    const int m = l & 15;
    const int quad = l >> 4;
    const int row_t0 = blockIdx.x * 128 + wv * 32;

    f4 acc[2][8];
    #pragma unroll
    for (int rt = 0; rt < 2; ++rt)
        #pragma unroll
        for (int ct = 0; ct < 8; ++ct)
            acc[rt][ct] = (f4){0.f, 0.f, 0.f, 0.f};

    int r0 = row_t0 + m;      if (r0 >= N) r0 = N - 1;   // clamp; stores guarded
    int r1 = row_t0 + 16 + m; if (r1 >= N) r1 = N - 1;

    #pragma unroll
    for (int ks = 0; ks < 4; ++ks) {
        int koff = ks * 32 + quad * 8;
        b8 a0 = *(const b8*)(A + (size_t)r0 * DIM + koff);
        b8 a1 = *(const b8*)(A + (size_t)r1 * DIM + koff);
        #pragma unroll
        for (int ct = 0; ct < 8; ++ct) {
            int c = ct * 16 + m;
            b8 bh = *(const b8*)(WH + c * WSTR + koff);
            b8 bl = *(const b8*)(WL + c * WSTR + koff);
            acc[0][ct] = __builtin_amdgcn_mfma_f32_16x16x32_bf16(a0, bh, acc[0][ct], 0, 0, 0);
            acc[0][ct] = __builtin_amdgcn_mfma_f32_16x16x32_bf16(a0, bl, acc[0][ct], 0, 0, 0);
            acc[1][ct] = __builtin_amdgcn_mfma_f32_16x16x32_bf16(a1, bh, acc[1][ct], 0, 0, 0);
            acc[1][ct] = __builtin_amdgcn_mfma_f32_16x16x32_bf16(a1, bl, acc[1][ct], 0, 0, 0);
        }
    }

    #pragma unroll
    for (int rt = 0; rt < 2; ++rt) {
        int rowb = row_t0 + rt * 16 + quad * 4;
        #pragma unroll
        for (int r = 0; r < 4; ++r) {
            int gr = rowb + r;
            if (gr < N) {
                float s = postscale ? postscale[gr] : 1.f;
                #pragma unroll
                for (int ct = 0; ct < 8; ++ct) {
                    int col = ct * 16 + m;
                    float v = fmaxf(acc[rt][ct][r] + bias[col], 0.f) * s;
                    if (outbf) outbf[(size_t)gr * DIM + col] = f2bf(v);
                    else       outf[(size_t)gr * DIM + col] = v;
                }
            }
        }
    }
}

static inline size_t align_up(size_t x, size_t a) { return (x + a - 1) & ~(a - 1); }

extern "C" void kernel_launch(void* const* d_in, const int* in_sizes, int n_in,
                              void* d_out, int out_size, void* d_ws, size_t ws_size,
                              hipStream_t stream) {
    const float* features = (const float*)d_in[0];
    const int*   src      = (const int*)d_in[1];
    const int*   dst      = (const int*)d_in[2];
    const float* W1       = (const float*)d_in[3];
    const float* b1       = (const float*)d_in[4];
    const float* W2       = (const float*)d_in[5];
    const float* b2       = (const float*)d_in[6];
    float* out = (float*)d_out;

    const int N = in_sizes[0] / DIM;
    const int E = in_sizes[1];
    const int B = (N + 255) / 256;
    const int W2w = (N + 1) >> 1;                 // packed histogram words
    const int slice = (E + HB - 1) / HB;
    const int cs_blocks = (W2w + 255) / 256;

    // workspace carve-up
    size_t nodeb = align_up((size_t)N * 4, 256);
    char* p = (char*)d_ws;
    int*   deg_out  = (int*)p;                      p += nodeb;
    int*   cnt      = (int*)p;                      p += nodeb;
    float* norm_src = (float*)p;                    p += nodeb;
    float* norm_dst = (float*)p;                    p += nodeb;
    int*   row_off  = (int*)p;                      p += align_up((size_t)(N + 1) * 4, 256);
    int*   bsum     = (int*)p;                      p += align_up((size_t)(2 * cs_blocks) * 4, 256);
    int*   bpre     = (int*)p;                      p += align_up((size_t)(2 * cs_blocks) * 4, 256);
    int*   csr_src  = (int*)p;                      p += align_up((size_t)E * 4, 256);
    char*  big      = p;                            p += 2 * (size_t)N * DIM * 4;  // 51.2 MB region
    unsigned short* w1hi = (unsigned short*)p;      p += (size_t)DIM * DIM * 2;
    unsigned short* w1lo = (unsigned short*)p;      p += (size_t)DIM * DIM * 2;
    unsigned short* w2hi = (unsigned short*)p;      p += (size_t)DIM * DIM * 2;
    unsigned short* w2lo = (unsigned short*)p;      p += (size_t)DIM * DIM * 2;
    // steady-state layout inside big:
    unsigned short* aggbf = (unsigned short*)big;                           // [0, 12.8 MB)
    unsigned short* h1bf  = (unsigned short*)(big + (size_t)N * DIM * 2);   // [12.8, 25.6)
    unsigned short* fbf   = (unsigned short*)(big + 3 * (size_t)N * DIM * 2); // [38.4, 51.2)
    // graph-build aliases over big[0, 38.0 MB) — disjoint from fbf:
    char* ap = big;
    unsigned short* local = (unsigned short*)ap;    ap += align_up((size_t)E * 2, 256);
    unsigned* hist_in  = (unsigned*)ap;             ap += (size_t)HB * W2w * 4;
    unsigned* hist_out = (unsigned*)ap;             ap += (size_t)HB * W2w * 4;
    unsigned* aux_in   = (unsigned*)ap;             ap += (size_t)NCH * W2w * 4;
    unsigned* aux_out  = (unsigned*)ap;             ap += (size_t)NCH * W2w * 4;
    int* local_fb = (int*)big;                      // fallback path only

    const int edge_blocks = (E + 255) / 256;
    const int spmm_blocks = (int)(((size_t)N * 32 + 255) / 256);
    const int gemm_blocks = (N + 127) / 128;
    const int n4 = N * (DIM / 4);
    const int cast_blocks = (n4 + 255) / 256;
    const int prep_blocks = (DIM * DIM + 255) / 256;

    // fast path requires: histogram fits LDS; graph aliases fit below fbf
    const bool fast = (W2w <= HWORDS) &&
        (align_up((size_t)E * 2, 256) + (2 * (size_t)HB + 2 * NCH) * W2w * 4
            <= 3 * (size_t)N * DIM * 2);

    // weight prep, both layers in one launch (outside alias region)
    k_prep<<<2 * prep_blocks, 256, 0, stream>>>(W1, W2, w1hi, w1lo, w2hi, w2lo, prep_blocks);

    if (fast) {
        k_hist<<<HB, 256, 0, stream>>>(src, dst, local, hist_in, hist_out, E, W2w, slice);
        k_colscan1<<<dim3(cs_blocks, NCH), 256, 0, stream>>>(hist_in, hist_out, aux_in, aux_out, W2w);
        k_colscan2<<<cs_blocks, 256, 0, stream>>>(aux_in, aux_out, cnt, deg_out, bsum, W2w, N);
        k_scan_small<<<1, 256, 0, stream>>>(bsum, bpre, B);
        k_scan_final<<<B, 256, 0, stream>>>(cnt, deg_out, bpre, row_off, norm_src, norm_dst, N);
        k_fill_cast<<<edge_blocks + cast_blocks, 256, 0, stream>>>(
            src, dst, row_off, local, (const int*)nullptr, hist_in, aux_in, csr_src,
            features, fbf, E, W2w, slice, edge_blocks, n4);
    } else {
        hipMemsetAsync(deg_out, 0, nodeb * 2, stream);
        k_edge_pass_fb<<<edge_blocks, 256, 0, stream>>>(src, dst, deg_out, cnt, local_fb, E);
        k_block_reduce<<<B, 256, 0, stream>>>(cnt, bsum, N);
        k_scan_small<<<1, 256, 0, stream>>>(bsum, bpre, B);
        k_scan_final<<<B, 256, 0, stream>>>(cnt, deg_out, bpre, row_off, norm_src, norm_dst, N);
        k_fill_cast<<<edge_blocks + cast_blocks, 256, 0, stream>>>(
            src, dst, row_off, (const unsigned short*)nullptr, local_fb,
            (const unsigned*)nullptr, (const unsigned*)nullptr, csr_src,
            features, fbf, E, W2w, slice, edge_blocks, n4);
    }

    // layer 1: bf16 gather (scaled by norm_src) -> aggbf; MFMA GEMM W1 -> h1bf
    // (epilogue pre-applies norm_src for layer 2)
    k_spmm<<<spmm_blocks, 256, 0, stream>>>(fbf, csr_src, row_off, norm_src, norm_dst, aggbf, N);
    k_gemm_mfma<<<gemm_blocks, 256, 0, stream>>>(aggbf, w1hi, w1lo, b1, norm_src,
                                                 (float*)nullptr, h1bf, N);

    // layer 2: bf16 gather of pre-scaled h1 -> aggbf; MFMA GEMM W2 -> out (fp32)
    k_spmm<<<spmm_blocks, 256, 0, stream>>>(h1bf, csr_src, row_off, (const float*)nullptr, norm_dst, aggbf, N);
    k_gemm_mfma<<<gemm_blocks, 256, 0, stream>>>(aggbf, w2hi, w2lo, b2, (const float*)nullptr,
                                                 out, (unsigned short*)nullptr, N);
}

// Round 13
// 226.124 us; speedup vs baseline: 1.4300x; 1.0253x over previous
//
#include <hip/hip_runtime.h>

#define DIM 128      // feature dim, fixed per reference
#define NCH 8        // colscan chunks
#define CH  22       // copies per chunk
#define HB  (NCH*CH) // 176 histogram copies (1 block/CU, 100KB LDS); frees tail for fbf
#define HWORDS 25088 // max padded (N+1)/2 supported by LDS histogram (100,352 B)
#define WSTR 136     // LDS stride for W tiles (bf16 elems): 16B aligned, 2-way banks

typedef __attribute__((ext_vector_type(8))) short b8;   // 8 bf16 (4 VGPRs)
typedef __attribute__((ext_vector_type(4))) float f4;   // MFMA acc

// bf16 helpers: RNE float->bf16, exact bf16->float
static __device__ __forceinline__ unsigned short f2bf(float f) {
    unsigned u = __float_as_uint(f);
    u += 0x7fffu + ((u >> 16) & 1u);
    return (unsigned short)(u >> 16);
}
static __device__ __forceinline__ float bf2f(unsigned short b) {
    return __uint_as_float((unsigned)b << 16);
}

// ---------------- LDS-privatized dual histogram + rank capture ----------------
// Zero/flush sweeps vectorized to uint4 (16B LDS ops + dwordx4 global streams).
// Rows strided W2p (mult of 4) so global uint4 stores stay 16B-aligned.
__global__ __launch_bounds__(256) void k_hist(const int* __restrict__ src,
                                              const int* __restrict__ dst,
                                              unsigned short* __restrict__ local,
                                              unsigned* __restrict__ hist_in,
                                              unsigned* __restrict__ hist_out,
                                              int E, int W2p, int slice) {
    __shared__ unsigned h[HWORDS];
    const int t = threadIdx.x;
    const int b = blockIdx.x;
    const int e0 = b * slice;
    const int e1 = min(e0 + slice, E);
    const int W4 = W2p >> 2;
    uint4* h4 = (uint4*)h;

    for (int w = t; w < W4; w += 256) h4[w] = make_uint4(0u, 0u, 0u, 0u);
    __syncthreads();
    for (int e = e0 + t; e < e1; e += 256) {
        int d = dst[e];
        unsigned sh = (unsigned)(d & 1) * 16u;
        unsigned old = atomicAdd(&h[d >> 1], 1u << sh);
        local[e] = (unsigned short)((old >> sh) & 0xffffu);
    }
    __syncthreads();
    uint4* oin = (uint4*)(hist_in + (size_t)b * W2p);
    for (int w = t; w < W4; w += 256) { oin[w] = h4[w]; h4[w] = make_uint4(0u, 0u, 0u, 0u); }
    __syncthreads();
    for (int e = e0 + t; e < e1; e += 256) {
        int s = src[e];
        atomicAdd(&h[s >> 1], 1u << ((unsigned)(s & 1) * 16u));
    }
    __syncthreads();
    uint4* oout = (uint4*)(hist_out + (size_t)b * W2p);
    for (int w = t; w < W4; w += 256) oout[w] = h4[w];
}

// ---------------- colscan pass 1: in-chunk exclusive prefix + chunk totals ----------------
__global__ __launch_bounds__(256) void k_colscan1(unsigned* __restrict__ hist_in,
                                                  const unsigned* __restrict__ hist_out,
                                                  unsigned* __restrict__ aux_in,
                                                  unsigned* __restrict__ aux_out,
                                                  int W2, int W2p) {
    int w = blockIdx.x * 256 + threadIdx.x;
    if (w >= W2) return;
    int ch = blockIdx.y;
    size_t base = (size_t)ch * CH * W2p + w;
    unsigned run = 0;
    #pragma unroll
    for (int b = 0; b < CH; ++b) {
        unsigned* p = hist_in + base + (size_t)b * W2p;
        unsigned x = *p;
        *p = run;          // in-chunk exclusive packed prefix
        run += x;          // halves independent (each < 65536)
    }
    aux_in[(size_t)ch * W2p + w] = run;
    unsigned run2 = 0;
    #pragma unroll
    for (int b = 0; b < CH; ++b) run2 += hist_out[base + (size_t)b * W2p];
    aux_out[(size_t)ch * W2p + w] = run2;
}

// ---------------- colscan pass 2 + fused block-reduce ----------------
__global__ __launch_bounds__(256) void k_colscan2(unsigned* __restrict__ aux_in,
                                                  const unsigned* __restrict__ aux_out,
                                                  int* __restrict__ cnt,
                                                  int* __restrict__ deg_out,
                                                  int* __restrict__ bsum,
                                                  int W2, int W2p, int N) {
    __shared__ int wsum[4];
    int w = blockIdx.x * 256 + threadIdx.x;
    unsigned run = 0, run2 = 0;
    if (w < W2) {
        #pragma unroll
        for (int ch = 0; ch < NCH; ++ch) {
            unsigned x = aux_in[(size_t)ch * W2p + w];
            aux_in[(size_t)ch * W2p + w] = run;   // chunk base
            run += x;
            run2 += aux_out[(size_t)ch * W2p + w];
        }
        int n0 = w * 2, n1 = n0 + 1;
        cnt[n0] = (int)(run & 0xffffu);
        deg_out[n0] = (int)(run2 & 0xffffu);
        if (n1 < N) {
            cnt[n1] = (int)(run >> 16);
            deg_out[n1] = (int)(run2 >> 16);
        } else {
            run &= 0xffffu;   // exclude phantom high half from bsum
        }
    }
    int tot = (int)(run & 0xffffu) + (int)(run >> 16);
    #pragma unroll
    for (int off = 32; off > 0; off >>= 1) tot += __shfl_down(tot, off, 64);
    int lane = threadIdx.x & 63, wave = threadIdx.x >> 6;
    if (lane == 0) wsum[wave] = tot;
    __syncthreads();
    if (threadIdx.x == 0)   bsum[2 * blockIdx.x]     = wsum[0] + wsum[1];
    if (threadIdx.x == 128) bsum[2 * blockIdx.x + 1] = wsum[2] + wsum[3];
}

// ---------------- fallback edge pass (global atomics) for oversized N ----------------
__global__ __launch_bounds__(256) void k_edge_pass_fb(const int* __restrict__ src,
                                                      const int* __restrict__ dst,
                                                      int* __restrict__ deg_out,
                                                      int* __restrict__ cnt,
                                                      int* __restrict__ local_fb, int E) {
    int e = blockIdx.x * 256 + threadIdx.x;
    if (e < E) {
        atomicAdd(&deg_out[src[e]], 1);
        local_fb[e] = atomicAdd(&cnt[dst[e]], 1);
    }
}

// ---------------- fallback block-reduce ----------------
__global__ __launch_bounds__(256) void k_block_reduce(const int* __restrict__ deg,
                                                      int* __restrict__ bsum, int N) {
    __shared__ int wsum[4];
    int i = blockIdx.x * 256 + threadIdx.x;
    int x = (i < N) ? deg[i] : 0;
    #pragma unroll
    for (int off = 32; off > 0; off >>= 1) x += __shfl_down(x, off, 64);
    int lane = threadIdx.x & 63, wave = threadIdx.x >> 6;
    if (lane == 0) wsum[wave] = x;
    __syncthreads();
    if (threadIdx.x == 0) bsum[blockIdx.x] = wsum[0] + wsum[1] + wsum[2] + wsum[3];
}

// ---------------- scan_final with inline block-prefix (scan_small fused) ----------------
// Each block sums bsum[0..bx) itself (B <= ~200: one strided pass), then does the
// block-local scan of cnt -> row_off + both norms.
__global__ __launch_bounds__(256) void k_scan_final(const int* __restrict__ cnt,
                                                    const int* __restrict__ deg_out,
                                                    const int* __restrict__ bsum,
                                                    int* __restrict__ row_off,
                                                    float* __restrict__ norm_src,
                                                    float* __restrict__ norm_dst, int N) {
    __shared__ int wsum[4];
    __shared__ int base_s;
    const int t = threadIdx.x;
    const int lane = t & 63, wave = t >> 6;

    // phase A: block prefix = sum of bsum[0..blockIdx.x)
    int pre = 0;
    for (int i = t; i < blockIdx.x; i += 256) pre += bsum[i];
    #pragma unroll
    for (int off = 32; off > 0; off >>= 1) pre += __shfl_down(pre, off, 64);
    if (lane == 0) wsum[wave] = pre;
    __syncthreads();
    if (t == 0) base_s = wsum[0] + wsum[1] + wsum[2] + wsum[3];
    __syncthreads();
    const int bpre_v = base_s;

    // phase B: block-local inclusive scan of cnt
    int i = blockIdx.x * 256 + t;
    int x = (i < N) ? cnt[i] : 0;
    int orig = x;
    #pragma unroll
    for (int off = 1; off < 64; off <<= 1) {
        int y = __shfl_up(x, off, 64);
        if (lane >= off) x += y;
    }
    if (lane == 63) wsum[wave] = x;
    __syncthreads();
    if (t == 0) {
        int s = 0;
        for (int w = 0; w < 4; ++w) { int tt = wsum[w]; wsum[w] = s; s += tt; }
    }
    __syncthreads();
    x += wsum[wave] + bpre_v;
    if (i < N) {
        row_off[i] = x - orig;
        int di = orig < 1 ? 1 : orig;
        norm_dst[i] = rsqrtf((float)di);
        int dov = deg_out[i]; if (dov < 1) dov = 1;
        norm_src[i] = rsqrtf((float)dov);
    }
    if (i == N - 1) row_off[N] = x;
}

// ---------------- fused: CSR fill + feature cast + weight prep ----------------
// blocks [0,eb): atomic-free scatter fill; [eb,eb+cb): fp32->bf16 feature cast;
// [eb+cb, eb+cb+2*pb): W1/W2 -> transposed bf16 hi/lo split.
__global__ __launch_bounds__(256) void k_fill_cast_prep(
        const int* __restrict__ src, const int* __restrict__ dst,
        const int* __restrict__ row_off,
        const unsigned short* __restrict__ local,
        const int* __restrict__ local_fb,
        const unsigned* __restrict__ hist_in,
        const unsigned* __restrict__ aux_in,
        int* __restrict__ csr_src,
        const float* __restrict__ feat, unsigned short* __restrict__ fbf,
        const float* __restrict__ W1, const float* __restrict__ W2,
        unsigned short* __restrict__ w1hi, unsigned short* __restrict__ w1lo,
        unsigned short* __restrict__ w2hi, unsigned short* __restrict__ w2lo,
        int E, int W2p, int slice, int eb, int cb, int pb, int n4) {
    int bx = blockIdx.x;
    if (bx < eb) {
        int e = bx * 256 + threadIdx.x;
        if (e < E) {
            int d = dst[e];
            int pos = row_off[d];
            if (hist_in) {
                int b = e / slice;
                int ch = b / CH;
                unsigned sh = (unsigned)(d & 1) * 16u;
                unsigned bo = (hist_in[(size_t)b * W2p + (d >> 1)] >> sh) & 0xffffu;
                unsigned cbs = (aux_in[(size_t)ch * W2p + (d >> 1)] >> sh) & 0xffffu;
                pos += (int)bo + (int)cbs + (int)local[e];
            } else {
                pos += local_fb[e];
            }
            csr_src[pos] = src[e];
        }
    } else if (bx < eb + cb) {
        int i = (bx - eb) * 256 + threadIdx.x;
        if (i < n4) {
            float4 v = ((const float4*)feat)[i];
            ushort4 o;
            o.x = f2bf(v.x); o.y = f2bf(v.y); o.z = f2bf(v.z); o.w = f2bf(v.w);
            ((ushort4*)fbf)[i] = o;
        }
    } else {
        int b = bx - eb - cb;
        const float* W; unsigned short *Hi, *Lo;
        if (b < pb) { W = W1; Hi = w1hi; Lo = w1lo; } else { W = W2; Hi = w2hi; Lo = w2lo; b -= pb; }
        int e = b * 256 + threadIdx.x;
        if (e < DIM * DIM) {
            int k = e >> 7, c = e & 127;
            float w = W[e];
            unsigned short hi = f2bf(w);
            unsigned short lo = f2bf(w - bf2f(hi));
            Hi[c * DIM + k] = hi;
            Lo[c * DIM + k] = lo;
        }
    }
}

// ---------------- CSR SpMM over bf16 rows -> bf16 agg ----------------
__global__ __launch_bounds__(256) void k_spmm(const unsigned short* __restrict__ hb,
                                              const int* __restrict__ csr_src,
                                              const int* __restrict__ row_off,
                                              const float* __restrict__ norm_src,
                                              const float* __restrict__ norm_dst,
                                              unsigned short* __restrict__ aggbf, int N) {
    int t = blockIdx.x * 256 + threadIdx.x;
    int node = t >> 5;
    int lane = t & 31;
    if (node >= N) return;
    int beg = row_off[node], end = row_off[node + 1];
    float4 acc0 = make_float4(0.f, 0.f, 0.f, 0.f);
    float4 acc1 = make_float4(0.f, 0.f, 0.f, 0.f);
    int i = beg;
    if (norm_src) {
        for (; i + 4 <= end; i += 4) {
            int s0 = csr_src[i], s1 = csr_src[i + 1], s2 = csr_src[i + 2], s3 = csr_src[i + 3];
            float n0 = norm_src[s0], n1 = norm_src[s1], n2 = norm_src[s2], n3 = norm_src[s3];
            ushort4 u0 = *((const ushort4*)(hb + (size_t)s0 * DIM) + lane);
            ushort4 u1 = *((const ushort4*)(hb + (size_t)s1 * DIM) + lane);
            ushort4 u2 = *((const ushort4*)(hb + (size_t)s2 * DIM) + lane);
            ushort4 u3 = *((const ushort4*)(hb + (size_t)s3 * DIM) + lane);
            acc0.x += bf2f(u0.x) * n0; acc0.y += bf2f(u0.y) * n0; acc0.z += bf2f(u0.z) * n0; acc0.w += bf2f(u0.w) * n0;
            acc1.x += bf2f(u1.x) * n1; acc1.y += bf2f(u1.y) * n1; acc1.z += bf2f(u1.z) * n1; acc1.w += bf2f(u1.w) * n1;
            acc0.x += bf2f(u2.x) * n2; acc0.y += bf2f(u2.y) * n2; acc0.z += bf2f(u2.z) * n2; acc0.w += bf2f(u2.w) * n2;
            acc1.x += bf2f(u3.x) * n3; acc1.y += bf2f(u3.y) * n3; acc1.z += bf2f(u3.z) * n3; acc1.w += bf2f(u3.w) * n3;
        }
        for (; i < end; ++i) {
            int s0 = csr_src[i];
            float n0 = norm_src[s0];
            ushort4 u0 = *((const ushort4*)(hb + (size_t)s0 * DIM) + lane);
            acc0.x += bf2f(u0.x) * n0; acc0.y += bf2f(u0.y) * n0; acc0.z += bf2f(u0.z) * n0; acc0.w += bf2f(u0.w) * n0;
        }
    } else {
        for (; i + 4 <= end; i += 4) {
            int s0 = csr_src[i], s1 = csr_src[i + 1], s2 = csr_src[i + 2], s3 = csr_src[i + 3];
            ushort4 u0 = *((const ushort4*)(hb + (size_t)s0 * DIM) + lane);
            ushort4 u1 = *((const ushort4*)(hb + (size_t)s1 * DIM) + lane);
            ushort4 u2 = *((const ushort4*)(hb + (size_t)s2 * DIM) + lane);
            ushort4 u3 = *((const ushort4*)(hb + (size_t)s3 * DIM) + lane);
            acc0.x += bf2f(u0.x); acc0.y += bf2f(u0.y); acc0.z += bf2f(u0.z); acc0.w += bf2f(u0.w);
            acc1.x += bf2f(u1.x); acc1.y += bf2f(u1.y); acc1.z += bf2f(u1.z); acc1.w += bf2f(u1.w);
            acc0.x += bf2f(u2.x); acc0.y += bf2f(u2.y); acc0.z += bf2f(u2.z); acc0.w += bf2f(u2.w);
            acc1.x += bf2f(u3.x); acc1.y += bf2f(u3.y); acc1.z += bf2f(u3.z); acc1.w += bf2f(u3.w);
        }
        for (; i < end; ++i) {
            int s0 = csr_src[i];
            ushort4 u0 = *((const ushort4*)(hb + (size_t)s0 * DIM) + lane);
            acc0.x += bf2f(u0.x); acc0.y += bf2f(u0.y); acc0.z += bf2f(u0.z); acc0.w += bf2f(u0.w);
        }
    }
    float nd = norm_dst[node];
    ushort4 o;
    o.x = f2bf((acc0.x + acc1.x) * nd);
    o.y = f2bf((acc0.y + acc1.y) * nd);
    o.z = f2bf((acc0.z + acc1.z) * nd);
    o.w = f2bf((acc0.w + acc1.w) * nd);
    *((ushort4*)(aggbf + (size_t)node * DIM) + lane) = o;
}

// ---------------- MFMA GEMM: out = [ps ⊙] relu(Abf @ (Whi+Wlo) + b) ----------------
__global__ __launch_bounds__(256, 2) void k_gemm_mfma(
        const unsigned short* __restrict__ A,      // [N][128] bf16
        const unsigned short* __restrict__ Wt_hi,  // [c][k] bf16
        const unsigned short* __restrict__ Wt_lo,
        const float* __restrict__ bias,
        const float* __restrict__ postscale,       // null => none
        float* __restrict__ outf, unsigned short* __restrict__ outbf, int N) {
    __shared__ unsigned short WH[DIM * WSTR];
    __shared__ unsigned short WL[DIM * WSTR];

    const int t = threadIdx.x;
    #pragma unroll
    for (int i = 0; i < 8; ++i) {
        int e = (t + i * 256) * 8;      // elem idx in [c][k] 128x128
        int c = e >> 7, k = e & 127;
        *(float4*)(WH + c * WSTR + k) = *(const float4*)(Wt_hi + e);
        *(float4*)(WL + c * WSTR + k) = *(const float4*)(Wt_lo + e);
    }
    __syncthreads();

    const int wv = t >> 6;
    const int l = t & 63;
    const int m = l & 15;
    const int quad = l >> 4;
    const int row_t0 = blockIdx.x * 128 + wv * 32;

    f4 acc[2][8];
    #pragma unroll
    for (int rt = 0; rt < 2; ++rt)
        #pragma unroll
        for (int ct = 0; ct < 8; ++ct)
            acc[rt][ct] = (f4){0.f, 0.f, 0.f, 0.f};

    int r0 = row_t0 + m;      if (r0 >= N) r0 = N - 1;   // clamp; stores guarded
    int r1 = row_t0 + 16 + m; if (r1 >= N) r1 = N - 1;

    #pragma unroll
    for (int ks = 0; ks < 4; ++ks) {
        int koff = ks * 32 + quad * 8;
        b8 a0 = *(const b8*)(A + (size_t)r0 * DIM + koff);
        b8 a1 = *(const b8*)(A + (size_t)r1 * DIM + koff);
        #pragma unroll
        for (int ct = 0; ct < 8; ++ct) {
            int c = ct * 16 + m;
            b8 bh = *(const b8*)(WH + c * WSTR + koff);
            b8 bl = *(const b8*)(WL + c * WSTR + koff);
            acc[0][ct] = __builtin_amdgcn_mfma_f32_16x16x32_bf16(a0, bh, acc[0][ct], 0, 0, 0);
            acc[0][ct] = __builtin_amdgcn_mfma_f32_16x16x32_bf16(a0, bl, acc[0][ct], 0, 0, 0);
            acc[1][ct] = __builtin_amdgcn_mfma_f32_16x16x32_bf16(a1, bh, acc[1][ct], 0, 0, 0);
            acc[1][ct] = __builtin_amdgcn_mfma_f32_16x16x32_bf16(a1, bl, acc[1][ct], 0, 0, 0);
        }
    }

    #pragma unroll
    for (int rt = 0; rt < 2; ++rt) {
        int rowb = row_t0 + rt * 16 + quad * 4;
        #pragma unroll
        for (int r = 0; r < 4; ++r) {
            int gr = rowb + r;
            if (gr < N) {
                float s = postscale ? postscale[gr] : 1.f;
                #pragma unroll
                for (int ct = 0; ct < 8; ++ct) {
                    int col = ct * 16 + m;
                    float v = fmaxf(acc[rt][ct][r] + bias[col], 0.f) * s;
                    if (outbf) outbf[(size_t)gr * DIM + col] = f2bf(v);
                    else       outf[(size_t)gr * DIM + col] = v;
                }
            }
        }
    }
}

static inline size_t align_up(size_t x, size_t a) { return (x + a - 1) & ~(a - 1); }

extern "C" void kernel_launch(void* const* d_in, const int* in_sizes, int n_in,
                              void* d_out, int out_size, void* d_ws, size_t ws_size,
                              hipStream_t stream) {
    const float* features = (const float*)d_in[0];
    const int*   src      = (const int*)d_in[1];
    const int*   dst      = (const int*)d_in[2];
    const float* W1       = (const float*)d_in[3];
    const float* b1       = (const float*)d_in[4];
    const float* W2       = (const float*)d_in[5];
    const float* b2       = (const float*)d_in[6];
    float* out = (float*)d_out;

    const int N = in_sizes[0] / DIM;
    const int E = in_sizes[1];
    const int B = (N + 255) / 256;
    const int W2w = (N + 1) >> 1;                 // packed histogram words
    const int W2p = (W2w + 3) & ~3;               // padded row stride (16B-aligned rows)
    const int slice = (E + HB - 1) / HB;
    const int cs_blocks = (W2w + 255) / 256;

    // workspace carve-up
    size_t nodeb = align_up((size_t)N * 4, 256);
    char* p = (char*)d_ws;
    int*   deg_out  = (int*)p;                      p += nodeb;
    int*   cnt      = (int*)p;                      p += nodeb;
    float* norm_src = (float*)p;                    p += nodeb;
    float* norm_dst = (float*)p;                    p += nodeb;
    int*   row_off  = (int*)p;                      p += align_up((size_t)(N + 1) * 4, 256);
    int*   bsum     = (int*)p;                      p += align_up((size_t)(2 * cs_blocks) * 4, 256);
    int*   csr_src  = (int*)p;                      p += align_up((size_t)E * 4, 256);
    char*  big      = p;                            p += 2 * (size_t)N * DIM * 4;  // 51.2 MB region
    unsigned short* w1hi = (unsigned short*)p;      p += (size_t)DIM * DIM * 2;
    unsigned short* w1lo = (unsigned short*)p;      p += (size_t)DIM * DIM * 2;
    unsigned short* w2hi = (unsigned short*)p;      p += (size_t)DIM * DIM * 2;
    unsigned short* w2lo = (unsigned short*)p;      p += (size_t)DIM * DIM * 2;
    // steady-state layout inside big:
    unsigned short* aggbf = (unsigned short*)big;                           // [0, 12.8 MB)
    unsigned short* h1bf  = (unsigned short*)(big + (size_t)N * DIM * 2);   // [12.8, 25.6)
    unsigned short* fbf   = (unsigned short*)(big + 3 * (size_t)N * DIM * 2); // [38.4, 51.2)
    // graph-build aliases over big[0, ~38 MB) — disjoint from fbf:
    char* ap = big;
    unsigned short* local = (unsigned short*)ap;    ap += align_up((size_t)E * 2, 256);
    unsigned* hist_in  = (unsigned*)ap;             ap += (size_t)HB * W2p * 4;
    unsigned* hist_out = (unsigned*)ap;             ap += (size_t)HB * W2p * 4;
    unsigned* aux_in   = (unsigned*)ap;             ap += (size_t)NCH * W2p * 4;
    unsigned* aux_out  = (unsigned*)ap;             ap += (size_t)NCH * W2p * 4;
    int* local_fb = (int*)big;                      // fallback path only

    const int edge_blocks = (E + 255) / 256;
    const int spmm_blocks = (int)(((size_t)N * 32 + 255) / 256);
    const int gemm_blocks = (N + 127) / 128;
    const int n4 = N * (DIM / 4);
    const int cast_blocks = (n4 + 255) / 256;
    const int prep_blocks = (DIM * DIM + 255) / 256;
    const int fcp_blocks  = edge_blocks + cast_blocks + 2 * prep_blocks;

    // fast path requires: padded histogram fits LDS; graph aliases fit below fbf
    const bool fast = (W2p <= HWORDS) &&
        (align_up((size_t)E * 2, 256) + (2 * (size_t)HB + 2 * NCH) * W2p * 4
            <= 3 * (size_t)N * DIM * 2);

    if (fast) {
        k_hist<<<HB, 256, 0, stream>>>(src, dst, local, hist_in, hist_out, E, W2p, slice);
        k_colscan1<<<dim3(cs_blocks, NCH), 256, 0, stream>>>(hist_in, hist_out, aux_in, aux_out, W2w, W2p);
        k_colscan2<<<cs_blocks, 256, 0, stream>>>(aux_in, aux_out, cnt, deg_out, bsum, W2w, W2p, N);
        k_scan_final<<<B, 256, 0, stream>>>(cnt, deg_out, bsum, row_off, norm_src, norm_dst, N);
        k_fill_cast_prep<<<fcp_blocks, 256, 0, stream>>>(
            src, dst, row_off, local, (const int*)nullptr, hist_in, aux_in, csr_src,
            features, fbf, W1, W2, w1hi, w1lo, w2hi, w2lo,
            E, W2p, slice, edge_blocks, cast_blocks, prep_blocks, n4);
    } else {
        hipMemsetAsync(deg_out, 0, nodeb * 2, stream);
        k_edge_pass_fb<<<edge_blocks, 256, 0, stream>>>(src, dst, deg_out, cnt, local_fb, E);
        k_block_reduce<<<B, 256, 0, stream>>>(cnt, bsum, N);
        k_scan_final<<<B, 256, 0, stream>>>(cnt, deg_out, bsum, row_off, norm_src, norm_dst, N);
        k_fill_cast_prep<<<fcp_blocks, 256, 0, stream>>>(
            src, dst, row_off, (const unsigned short*)nullptr, local_fb,
            (const unsigned*)nullptr, (const unsigned*)nullptr, csr_src,
            features, fbf, W1, W2, w1hi, w1lo, w2hi, w2lo,
            E, W2p, slice, edge_blocks, cast_blocks, prep_blocks, n4);
    }

    // layer 1: bf16 gather (scaled by norm_src) -> aggbf; MFMA GEMM W1 -> h1bf
    // (epilogue pre-applies norm_src for layer 2)
    k_spmm<<<spmm_blocks, 256, 0, stream>>>(fbf, csr_src, row_off, norm_src, norm_dst, aggbf, N);
    k_gemm_mfma<<<gemm_blocks, 256, 0, stream>>>(aggbf, w1hi, w1lo, b1, norm_src,
                                                 (float*)nullptr, h1bf, N);

    // layer 2: bf16 gather of pre-scaled h1 -> aggbf; MFMA GEMM W2 -> out (fp32)
    k_spmm<<<spmm_blocks, 256, 0, stream>>>(h1bf, csr_src, row_off, (const float*)nullptr, norm_dst, aggbf, N);
    k_gemm_mfma<<<gemm_blocks, 256, 0, stream>>>(aggbf, w2hi, w2lo, b2, (const float*)nullptr,
                                                 out, (unsigned short*)nullptr, N);
}

// Round 14
// 216.800 us; speedup vs baseline: 1.4915x; 1.0430x over previous
//
#include <hip/hip_runtime.h>

#define DIM 128      // feature dim, fixed per reference
#define NCH 8        // colscan chunks
#define CH  22       // copies per chunk
#define HB  (NCH*CH) // 176 histogram copies (1 block/CU, 100KB LDS); frees tail for fbf
#define HWORDS 25088 // max padded (N+1)/2 supported by LDS histogram (100,352 B)
#define WSTR 136     // LDS stride for W tiles (bf16 elems): 16B aligned, 2-way banks

typedef __attribute__((ext_vector_type(8))) short b8;            // 8 bf16 (4 VGPRs)
typedef __attribute__((ext_vector_type(4))) float f4;            // MFMA acc
typedef __attribute__((ext_vector_type(8))) unsigned short u16x8; // 16B bf16 chunk

// bf16 helpers: RNE float->bf16, exact bf16->float
static __device__ __forceinline__ unsigned short f2bf(float f) {
    unsigned u = __float_as_uint(f);
    u += 0x7fffu + ((u >> 16) & 1u);
    return (unsigned short)(u >> 16);
}
static __device__ __forceinline__ float bf2f(unsigned short b) {
    return __uint_as_float((unsigned)b << 16);
}

// ---------------- LDS-privatized dual histogram + rank capture ----------------
__global__ __launch_bounds__(256) void k_hist(const int* __restrict__ src,
                                              const int* __restrict__ dst,
                                              unsigned short* __restrict__ local,
                                              unsigned* __restrict__ hist_in,
                                              unsigned* __restrict__ hist_out,
                                              int E, int W2p, int slice) {
    __shared__ unsigned h[HWORDS];
    const int t = threadIdx.x;
    const int b = blockIdx.x;
    const int e0 = b * slice;
    const int e1 = min(e0 + slice, E);
    const int W4 = W2p >> 2;
    uint4* h4 = (uint4*)h;

    for (int w = t; w < W4; w += 256) h4[w] = make_uint4(0u, 0u, 0u, 0u);
    __syncthreads();
    for (int e = e0 + t; e < e1; e += 256) {
        int d = dst[e];
        unsigned sh = (unsigned)(d & 1) * 16u;
        unsigned old = atomicAdd(&h[d >> 1], 1u << sh);
        local[e] = (unsigned short)((old >> sh) & 0xffffu);
    }
    __syncthreads();
    uint4* oin = (uint4*)(hist_in + (size_t)b * W2p);
    for (int w = t; w < W4; w += 256) { oin[w] = h4[w]; h4[w] = make_uint4(0u, 0u, 0u, 0u); }
    __syncthreads();
    for (int e = e0 + t; e < e1; e += 256) {
        int s = src[e];
        atomicAdd(&h[s >> 1], 1u << ((unsigned)(s & 1) * 16u));
    }
    __syncthreads();
    uint4* oout = (uint4*)(hist_out + (size_t)b * W2p);
    for (int w = t; w < W4; w += 256) oout[w] = h4[w];
}

// ---------------- colscan pass 1: in-chunk exclusive prefix + chunk totals ----------------
__global__ __launch_bounds__(256) void k_colscan1(unsigned* __restrict__ hist_in,
                                                  const unsigned* __restrict__ hist_out,
                                                  unsigned* __restrict__ aux_in,
                                                  unsigned* __restrict__ aux_out,
                                                  int W2, int W2p) {
    int w = blockIdx.x * 256 + threadIdx.x;
    if (w >= W2) return;
    int ch = blockIdx.y;
    size_t base = (size_t)ch * CH * W2p + w;
    unsigned run = 0;
    #pragma unroll
    for (int b = 0; b < CH; ++b) {
        unsigned* p = hist_in + base + (size_t)b * W2p;
        unsigned x = *p;
        *p = run;          // in-chunk exclusive packed prefix
        run += x;          // halves independent (each < 65536)
    }
    aux_in[(size_t)ch * W2p + w] = run;
    unsigned run2 = 0;
    #pragma unroll
    for (int b = 0; b < CH; ++b) run2 += hist_out[base + (size_t)b * W2p];
    aux_out[(size_t)ch * W2p + w] = run2;
}

// ---------------- colscan pass 2 + fused block-reduce ----------------
__global__ __launch_bounds__(256) void k_colscan2(unsigned* __restrict__ aux_in,
                                                  const unsigned* __restrict__ aux_out,
                                                  int* __restrict__ cnt,
                                                  int* __restrict__ deg_out,
                                                  int* __restrict__ bsum,
                                                  int W2, int W2p, int N) {
    __shared__ int wsum[4];
    int w = blockIdx.x * 256 + threadIdx.x;
    unsigned run = 0, run2 = 0;
    if (w < W2) {
        #pragma unroll
        for (int ch = 0; ch < NCH; ++ch) {
            unsigned x = aux_in[(size_t)ch * W2p + w];
            aux_in[(size_t)ch * W2p + w] = run;   // chunk base
            run += x;
            run2 += aux_out[(size_t)ch * W2p + w];
        }
        int n0 = w * 2, n1 = n0 + 1;
        cnt[n0] = (int)(run & 0xffffu);
        deg_out[n0] = (int)(run2 & 0xffffu);
        if (n1 < N) {
            cnt[n1] = (int)(run >> 16);
            deg_out[n1] = (int)(run2 >> 16);
        } else {
            run &= 0xffffu;   // exclude phantom high half from bsum
        }
    }
    int tot = (int)(run & 0xffffu) + (int)(run >> 16);
    #pragma unroll
    for (int off = 32; off > 0; off >>= 1) tot += __shfl_down(tot, off, 64);
    int lane = threadIdx.x & 63, wave = threadIdx.x >> 6;
    if (lane == 0) wsum[wave] = tot;
    __syncthreads();
    if (threadIdx.x == 0)   bsum[2 * blockIdx.x]     = wsum[0] + wsum[1];
    if (threadIdx.x == 128) bsum[2 * blockIdx.x + 1] = wsum[2] + wsum[3];
}

// ---------------- fallback edge pass (global atomics) for oversized N ----------------
__global__ __launch_bounds__(256) void k_edge_pass_fb(const int* __restrict__ src,
                                                      const int* __restrict__ dst,
                                                      int* __restrict__ deg_out,
                                                      int* __restrict__ cnt,
                                                      int* __restrict__ local_fb, int E) {
    int e = blockIdx.x * 256 + threadIdx.x;
    if (e < E) {
        atomicAdd(&deg_out[src[e]], 1);
        local_fb[e] = atomicAdd(&cnt[dst[e]], 1);
    }
}

// ---------------- fallback block-reduce ----------------
__global__ __launch_bounds__(256) void k_block_reduce(const int* __restrict__ deg,
                                                      int* __restrict__ bsum, int N) {
    __shared__ int wsum[4];
    int i = blockIdx.x * 256 + threadIdx.x;
    int x = (i < N) ? deg[i] : 0;
    #pragma unroll
    for (int off = 32; off > 0; off >>= 1) x += __shfl_down(x, off, 64);
    int lane = threadIdx.x & 63, wave = threadIdx.x >> 6;
    if (lane == 0) wsum[wave] = x;
    __syncthreads();
    if (threadIdx.x == 0) bsum[blockIdx.x] = wsum[0] + wsum[1] + wsum[2] + wsum[3];
}

// ---------------- scan_final with inline block-prefix ----------------
__global__ __launch_bounds__(256) void k_scan_final(const int* __restrict__ cnt,
                                                    const int* __restrict__ deg_out,
                                                    const int* __restrict__ bsum,
                                                    int* __restrict__ row_off,
                                                    float* __restrict__ norm_src,
                                                    float* __restrict__ norm_dst, int N) {
    __shared__ int wsum[4];
    __shared__ int base_s;
    const int t = threadIdx.x;
    const int lane = t & 63, wave = t >> 6;

    int pre = 0;
    for (int i = t; i < blockIdx.x; i += 256) pre += bsum[i];
    #pragma unroll
    for (int off = 32; off > 0; off >>= 1) pre += __shfl_down(pre, off, 64);
    if (lane == 0) wsum[wave] = pre;
    __syncthreads();
    if (t == 0) base_s = wsum[0] + wsum[1] + wsum[2] + wsum[3];
    __syncthreads();
    const int bpre_v = base_s;

    int i = blockIdx.x * 256 + t;
    int x = (i < N) ? cnt[i] : 0;
    int orig = x;
    #pragma unroll
    for (int off = 1; off < 64; off <<= 1) {
        int y = __shfl_up(x, off, 64);
        if (lane >= off) x += y;
    }
    if (lane == 63) wsum[wave] = x;
    __syncthreads();
    if (t == 0) {
        int s = 0;
        for (int w = 0; w < 4; ++w) { int tt = wsum[w]; wsum[w] = s; s += tt; }
    }
    __syncthreads();
    x += wsum[wave] + bpre_v;
    if (i < N) {
        row_off[i] = x - orig;
        int di = orig < 1 ? 1 : orig;
        norm_dst[i] = rsqrtf((float)di);
        int dov = deg_out[i]; if (dov < 1) dov = 1;
        norm_src[i] = rsqrtf((float)dov);
    }
    if (i == N - 1) row_off[N] = x;
}

// ---------------- fused: CSR fill + prescaled feature cast + weight prep ----------------
// blocks [0,eb): atomic-free scatter fill; [eb,eb+cb): fp32->bf16 cast of
// features*norm_src (norms ready: runs after k_scan_final); [eb+cb, +2*pb): W prep.
__global__ __launch_bounds__(256) void k_fill_cast_prep(
        const int* __restrict__ src, const int* __restrict__ dst,
        const int* __restrict__ row_off,
        const unsigned short* __restrict__ local,
        const int* __restrict__ local_fb,
        const unsigned* __restrict__ hist_in,
        const unsigned* __restrict__ aux_in,
        int* __restrict__ csr_src,
        const float* __restrict__ feat, const float* __restrict__ norm_src,
        unsigned short* __restrict__ fbf,
        const float* __restrict__ W1, const float* __restrict__ W2,
        unsigned short* __restrict__ w1hi, unsigned short* __restrict__ w1lo,
        unsigned short* __restrict__ w2hi, unsigned short* __restrict__ w2lo,
        int E, int W2p, int slice, int eb, int cb, int pb, int n4) {
    int bx = blockIdx.x;
    if (bx < eb) {
        int e = bx * 256 + threadIdx.x;
        if (e < E) {
            int d = dst[e];
            int pos = row_off[d];
            if (hist_in) {
                int b = e / slice;
                int ch = b / CH;
                unsigned sh = (unsigned)(d & 1) * 16u;
                unsigned bo = (hist_in[(size_t)b * W2p + (d >> 1)] >> sh) & 0xffffu;
                unsigned cbs = (aux_in[(size_t)ch * W2p + (d >> 1)] >> sh) & 0xffffu;
                pos += (int)bo + (int)cbs + (int)local[e];
            } else {
                pos += local_fb[e];
            }
            csr_src[pos] = src[e];
        }
    } else if (bx < eb + cb) {
        int i = (bx - eb) * 256 + threadIdx.x;
        if (i < n4) {
            float4 v = ((const float4*)feat)[i];
            float ns = norm_src[i >> 5];   // 32 float4 per node row
            ushort4 o;
            o.x = f2bf(v.x * ns); o.y = f2bf(v.y * ns);
            o.z = f2bf(v.z * ns); o.w = f2bf(v.w * ns);
            ((ushort4*)fbf)[i] = o;
        }
    } else {
        int b = bx - eb - cb;
        const float* W; unsigned short *Hi, *Lo;
        if (b < pb) { W = W1; Hi = w1hi; Lo = w1lo; } else { W = W2; Hi = w2hi; Lo = w2lo; b -= pb; }
        int e = b * 256 + threadIdx.x;
        if (e < DIM * DIM) {
            int k = e >> 7, c = e & 127;
            float w = W[e];
            unsigned short hi = f2bf(w);
            unsigned short lo = f2bf(w - bf2f(hi));
            Hi[c * DIM + k] = hi;
            Lo[c * DIM + k] = lo;
        }
    }
}

// ---------------- CSR SpMM over pre-scaled bf16 rows -> bf16 agg ----------------
// 16 lanes per node, u16x8 (8 bf16, 16B) per lane -> 256B/row; 4 nodes/wave,
// 16 outstanding gathers/wave at 4-deep unroll; fp32 accumulate; bf16 out.
__global__ __launch_bounds__(256) void k_spmm(const unsigned short* __restrict__ hb,
                                              const int* __restrict__ csr_src,
                                              const int* __restrict__ row_off,
                                              const float* __restrict__ norm_dst,
                                              unsigned short* __restrict__ aggbf, int N) {
    int t = blockIdx.x * 256 + threadIdx.x;
    int node = t >> 4;
    int lane = t & 15;
    if (node >= N) return;
    int beg = row_off[node], end = row_off[node + 1];
    float a0[8] = {0.f, 0.f, 0.f, 0.f, 0.f, 0.f, 0.f, 0.f};
    float a1[8] = {0.f, 0.f, 0.f, 0.f, 0.f, 0.f, 0.f, 0.f};
    int i = beg;
    for (; i + 4 <= end; i += 4) {
        int s0 = csr_src[i], s1 = csr_src[i + 1], s2 = csr_src[i + 2], s3 = csr_src[i + 3];
        u16x8 u0 = *((const u16x8*)(hb + (size_t)s0 * DIM) + lane);
        u16x8 u1 = *((const u16x8*)(hb + (size_t)s1 * DIM) + lane);
        u16x8 u2 = *((const u16x8*)(hb + (size_t)s2 * DIM) + lane);
        u16x8 u3 = *((const u16x8*)(hb + (size_t)s3 * DIM) + lane);
        #pragma unroll
        for (int j = 0; j < 8; ++j) {
            a0[j] += bf2f(u0[j]);
            a1[j] += bf2f(u1[j]);
            a0[j] += bf2f(u2[j]);
            a1[j] += bf2f(u3[j]);
        }
    }
    for (; i < end; ++i) {
        int s0 = csr_src[i];
        u16x8 u0 = *((const u16x8*)(hb + (size_t)s0 * DIM) + lane);
        #pragma unroll
        for (int j = 0; j < 8; ++j) a0[j] += bf2f(u0[j]);
    }
    float nd = norm_dst[node];
    u16x8 o;
    #pragma unroll
    for (int j = 0; j < 8; ++j) o[j] = f2bf((a0[j] + a1[j]) * nd);
    *((u16x8*)(aggbf + (size_t)node * DIM) + lane) = o;
}

// ---------------- MFMA GEMM: out = [ps ⊙] relu(Abf @ (Whi+Wlo) + b) ----------------
__global__ __launch_bounds__(256, 2) void k_gemm_mfma(
        const unsigned short* __restrict__ A,      // [N][128] bf16
        const unsigned short* __restrict__ Wt_hi,  // [c][k] bf16
        const unsigned short* __restrict__ Wt_lo,
        const float* __restrict__ bias,
        const float* __restrict__ postscale,       // null => none
        float* __restrict__ outf, unsigned short* __restrict__ outbf, int N) {
    __shared__ unsigned short WH[DIM * WSTR];
    __shared__ unsigned short WL[DIM * WSTR];

    const int t = threadIdx.x;
    #pragma unroll
    for (int i = 0; i < 8; ++i) {
        int e = (t + i * 256) * 8;      // elem idx in [c][k] 128x128
        int c = e >> 7, k = e & 127;
        *(float4*)(WH + c * WSTR + k) = *(const float4*)(Wt_hi + e);
        *(float4*)(WL + c * WSTR + k) = *(const float4*)(Wt_lo + e);
    }
    __syncthreads();

    const int wv = t >> 6;
    const int l = t & 63;
    const int m = l & 15;
    const int quad = l >> 4;
    const int row_t0 = blockIdx.x * 128 + wv * 32;

    f4 acc[2][8];
    #pragma unroll
    for (int rt = 0; rt < 2; ++rt)
        #pragma unroll
        for (int ct = 0; ct < 8; ++ct)
            acc[rt][ct] = (f4){0.f, 0.f, 0.f, 0.f};

    int r0 = row_t0 + m;      if (r0 >= N) r0 = N - 1;   // clamp; stores guarded
    int r1 = row_t0 + 16 + m; if (r1 >= N) r1 = N - 1;

    #pragma unroll
    for (int ks = 0; ks < 4; ++ks) {
        int koff = ks * 32 + quad * 8;
        b8 a0 = *(const b8*)(A + (size_t)r0 * DIM + koff);
        b8 a1 = *(const b8*)(A + (size_t)r1 * DIM + koff);
        #pragma unroll
        for (int ct = 0; ct < 8; ++ct) {
            int c = ct * 16 + m;
            b8 bh = *(const b8*)(WH + c * WSTR + koff);
            b8 bl = *(const b8*)(WL + c * WSTR + koff);
            acc[0][ct] = __builtin_amdgcn_mfma_f32_16x16x32_bf16(a0, bh, acc[0][ct], 0, 0, 0);
            acc[0][ct] = __builtin_amdgcn_mfma_f32_16x16x32_bf16(a0, bl, acc[0][ct], 0, 0, 0);
            acc[1][ct] = __builtin_amdgcn_mfma_f32_16x16x32_bf16(a1, bh, acc[1][ct], 0, 0, 0);
            acc[1][ct] = __builtin_amdgcn_mfma_f32_16x16x32_bf16(a1, bl, acc[1][ct], 0, 0, 0);
        }
    }

    #pragma unroll
    for (int rt = 0; rt < 2; ++rt) {
        int rowb = row_t0 + rt * 16 + quad * 4;
        #pragma unroll
        for (int r = 0; r < 4; ++r) {
            int gr = rowb + r;
            if (gr < N) {
                float s = postscale ? postscale[gr] : 1.f;
                #pragma unroll
                for (int ct = 0; ct < 8; ++ct) {
                    int col = ct * 16 + m;
                    float v = fmaxf(acc[rt][ct][r] + bias[col], 0.f) * s;
                    if (outbf) outbf[(size_t)gr * DIM + col] = f2bf(v);
                    else       outf[(size_t)gr * DIM + col] = v;
                }
            }
        }
    }
}

static inline size_t align_up(size_t x, size_t a) { return (x + a - 1) & ~(a - 1); }

extern "C" void kernel_launch(void* const* d_in, const int* in_sizes, int n_in,
                              void* d_out, int out_size, void* d_ws, size_t ws_size,
                              hipStream_t stream) {
    const float* features = (const float*)d_in[0];
    const int*   src      = (const int*)d_in[1];
    const int*   dst      = (const int*)d_in[2];
    const float* W1       = (const float*)d_in[3];
    const float* b1       = (const float*)d_in[4];
    const float* W2       = (const float*)d_in[5];
    const float* b2       = (const float*)d_in[6];
    float* out = (float*)d_out;

    const int N = in_sizes[0] / DIM;
    const int E = in_sizes[1];
    const int B = (N + 255) / 256;
    const int W2w = (N + 1) >> 1;                 // packed histogram words
    const int W2p = (W2w + 3) & ~3;               // padded row stride (16B-aligned rows)
    const int slice = (E + HB - 1) / HB;
    const int cs_blocks = (W2w + 255) / 256;

    // workspace carve-up
    size_t nodeb = align_up((size_t)N * 4, 256);
    char* p = (char*)d_ws;
    int*   deg_out  = (int*)p;                      p += nodeb;
    int*   cnt      = (int*)p;                      p += nodeb;
    float* norm_src = (float*)p;                    p += nodeb;
    float* norm_dst = (float*)p;                    p += nodeb;
    int*   row_off  = (int*)p;                      p += align_up((size_t)(N + 1) * 4, 256);
    int*   bsum     = (int*)p;                      p += align_up((size_t)(2 * cs_blocks) * 4, 256);
    int*   csr_src  = (int*)p;                      p += align_up((size_t)E * 4, 256);
    char*  big      = p;                            p += 2 * (size_t)N * DIM * 4;  // 51.2 MB region
    unsigned short* w1hi = (unsigned short*)p;      p += (size_t)DIM * DIM * 2;
    unsigned short* w1lo = (unsigned short*)p;      p += (size_t)DIM * DIM * 2;
    unsigned short* w2hi = (unsigned short*)p;      p += (size_t)DIM * DIM * 2;
    unsigned short* w2lo = (unsigned short*)p;      p += (size_t)DIM * DIM * 2;
    // steady-state layout inside big:
    unsigned short* aggbf = (unsigned short*)big;                           // [0, 12.8 MB)
    unsigned short* h1bf  = (unsigned short*)(big + (size_t)N * DIM * 2);   // [12.8, 25.6)
    unsigned short* fbf   = (unsigned short*)(big + 3 * (size_t)N * DIM * 2); // [38.4, 51.2)
    // graph-build aliases over big[0, ~38 MB) — disjoint from fbf:
    char* ap = big;
    unsigned short* local = (unsigned short*)ap;    ap += align_up((size_t)E * 2, 256);
    unsigned* hist_in  = (unsigned*)ap;             ap += (size_t)HB * W2p * 4;
    unsigned* hist_out = (unsigned*)ap;             ap += (size_t)HB * W2p * 4;
    unsigned* aux_in   = (unsigned*)ap;             ap += (size_t)NCH * W2p * 4;
    unsigned* aux_out  = (unsigned*)ap;             ap += (size_t)NCH * W2p * 4;
    int* local_fb = (int*)big;                      // fallback path only

    const int edge_blocks = (E + 255) / 256;
    const int spmm_blocks = (int)(((size_t)N * 16 + 255) / 256);
    const int gemm_blocks = (N + 127) / 128;
    const int n4 = N * (DIM / 4);
    const int cast_blocks = (n4 + 255) / 256;
    const int prep_blocks = (DIM * DIM + 255) / 256;
    const int fcp_blocks  = edge_blocks + cast_blocks + 2 * prep_blocks;

    // fast path requires: padded histogram fits LDS; graph aliases fit below fbf
    const bool fast = (W2p <= HWORDS) &&
        (align_up((size_t)E * 2, 256) + (2 * (size_t)HB + 2 * NCH) * W2p * 4
            <= 3 * (size_t)N * DIM * 2);

    if (fast) {
        k_hist<<<HB, 256, 0, stream>>>(src, dst, local, hist_in, hist_out, E, W2p, slice);
        k_colscan1<<<dim3(cs_blocks, NCH), 256, 0, stream>>>(hist_in, hist_out, aux_in, aux_out, W2w, W2p);
        k_colscan2<<<cs_blocks, 256, 0, stream>>>(aux_in, aux_out, cnt, deg_out, bsum, W2w, W2p, N);
        k_scan_final<<<B, 256, 0, stream>>>(cnt, deg_out, bsum, row_off, norm_src, norm_dst, N);
        k_fill_cast_prep<<<fcp_blocks, 256, 0, stream>>>(
            src, dst, row_off, local, (const int*)nullptr, hist_in, aux_in, csr_src,
            features, norm_src, fbf, W1, W2, w1hi, w1lo, w2hi, w2lo,
            E, W2p, slice, edge_blocks, cast_blocks, prep_blocks, n4);
    } else {
        hipMemsetAsync(deg_out, 0, nodeb * 2, stream);
        k_edge_pass_fb<<<edge_blocks, 256, 0, stream>>>(src, dst, deg_out, cnt, local_fb, E);
        k_block_reduce<<<B, 256, 0, stream>>>(cnt, bsum, N);
        k_scan_final<<<B, 256, 0, stream>>>(cnt, deg_out, bsum, row_off, norm_src, norm_dst, N);
        k_fill_cast_prep<<<fcp_blocks, 256, 0, stream>>>(
            src, dst, row_off, (const unsigned short*)nullptr, local_fb,
            (const unsigned*)nullptr, (const unsigned*)nullptr, csr_src,
            features, norm_src, fbf, W1, W2, w1hi, w1lo, w2hi, w2lo,
            E, W2p, slice, edge_blocks, cast_blocks, prep_blocks, n4);
    }

    // layer 1: fbf already carries norm_src; gather -> aggbf; MFMA GEMM W1 -> h1bf
    // (epilogue pre-applies norm_src for layer 2's gather)
    k_spmm<<<spmm_blocks, 256, 0, stream>>>(fbf, csr_src, row_off, norm_dst, aggbf, N);
    k_gemm_mfma<<<gemm_blocks, 256, 0, stream>>>(aggbf, w1hi, w1lo, b1, norm_src,
                                                 (float*)nullptr, h1bf, N);

    // layer 2: gather pre-scaled h1 -> aggbf; MFMA GEMM W2 -> out (fp32)
    k_spmm<<<spmm_blocks, 256, 0, stream>>>(h1bf, csr_src, row_off, norm_dst, aggbf, N);
    k_gemm_mfma<<<gemm_blocks, 256, 0, stream>>>(aggbf, w2hi, w2lo, b2, (const float*)nullptr,
                                                 out, (unsigned short*)nullptr, N);
}